// Round 5
// baseline (330.048 us; speedup 1.0000x reference)
//
#include <hip/hip_runtime.h>
#include <stdint.h>

#define Bsz  8192
#define DMOD 512
#define NE   4
#define NP   1024
#define NF   2048
#define MAXTILES 70   // sum_b ceil(cnt_b/128) <= 8192/128 + 6 buckets

typedef float  f32x4  __attribute__((ext_vector_type(4)));
typedef __bf16 bf16x8 __attribute__((ext_vector_type(8)));
typedef unsigned short u16x8 __attribute__((ext_vector_type(8)));

typedef __attribute__((address_space(3))) void       lds_void;
typedef const __attribute__((address_space(1))) void glb_void;
#define GLOAD16(gp, lp) \
  __builtin_amdgcn_global_load_lds((glb_void*)(gp), (lds_void*)(lp), 16, 0, 0)

__device__ __forceinline__ unsigned short f32_bf16(float f) {
  unsigned int u = __float_as_uint(f);
  u += 0x7FFFu + ((u >> 16) & 1u);   // round-to-nearest-even
  return (unsigned short)(u >> 16);
}

// ---------------- kernel 0: zero the counters ----------------
__global__ void init_kernel(int* __restrict__ cnt, double* __restrict__ lossAcc) {
  if (threadIdx.x < 6) cnt[threadIdx.x] = 0;
  if (threadIdx.x == 0) *lossAcc = 0.0;
}

// ---------------- kernel 1: concat+cvt + gate (softmax/top2) + pair histogram ----------------
__global__ __launch_bounds__(256) void fuse_gate(
    const float* __restrict__ x0, const float* __restrict__ x1,
    const float* __restrict__ x2, const float* __restrict__ x3,
    const float* __restrict__ Wg,
    unsigned short* __restrict__ fusedB, float* __restrict__ gw,
    int* __restrict__ pair, int* __restrict__ cnt)
{
  __shared__ float sred[4][4];
  const int b   = blockIdx.x;
  const int tid = threadIdx.x;
  const int f   = tid * 8;
  const float* xm  = (f < 1024) ? (f < 512 ? x0 : x1) : (f < 1536 ? x2 : x3);
  const float* src = xm + (size_t)b * DMOD + (f & 511);
  float4 v0 = *(const float4*)src;
  float4 v1 = *(const float4*)(src + 4);
  u16x8 o;
  o[0] = f32_bf16(v0.x); o[1] = f32_bf16(v0.y); o[2] = f32_bf16(v0.z); o[3] = f32_bf16(v0.w);
  o[4] = f32_bf16(v1.x); o[5] = f32_bf16(v1.y); o[6] = f32_bf16(v1.z); o[7] = f32_bf16(v1.w);
  *(u16x8*)(fusedB + (size_t)b * NF + f) = o;

  float d[4];
  #pragma unroll
  for (int e = 0; e < 4; ++e) {
    const float* w = Wg + e * NF + f;
    d[e] = v0.x * w[0] + v0.y * w[1] + v0.z * w[2] + v0.w * w[3]
         + v1.x * w[4] + v1.y * w[5] + v1.z * w[6] + v1.w * w[7];
  }
  #pragma unroll
  for (int off = 32; off; off >>= 1) {
    #pragma unroll
    for (int e = 0; e < 4; ++e) d[e] += __shfl_xor(d[e], off);
  }
  if ((tid & 63) == 0) {
    #pragma unroll
    for (int e = 0; e < 4; ++e) sred[tid >> 6][e] = d[e];
  }
  __syncthreads();
  if (tid == 0) {
    float a0 = sred[0][0] + sred[1][0] + sred[2][0] + sred[3][0];
    float a1 = sred[0][1] + sred[1][1] + sred[2][1] + sred[3][1];
    float a2 = sred[0][2] + sred[1][2] + sred[2][2] + sred[3][2];
    float a3 = sred[0][3] + sred[1][3] + sred[2][3] + sred[3][3];
    float m  = fmaxf(fmaxf(a0, a1), fmaxf(a2, a3));
    float e0 = expf(a0 - m), e1 = expf(a1 - m), e2 = expf(a2 - m), e3 = expf(a3 - m);
    float inv = 1.f / (e0 + e1 + e2 + e3);
    float p0 = e0 * inv, p1 = e1 * inv, p2 = e2 * inv, p3 = e3 * inv;
    // top-2, jax tie-break (lower index wins on ties -> strict >)
    int i1 = 0; float b1 = a0;
    if (a1 > b1) { b1 = a1; i1 = 1; }
    if (a2 > b1) { b1 = a2; i1 = 2; }
    if (a3 > b1) { b1 = a3; i1 = 3; }
    int i2 = -1; float b2 = -3.4e38f;
    if (i1 != 0 && a0 > b2) { b2 = a0; i2 = 0; }
    if (i1 != 1 && a1 > b2) { b2 = a1; i2 = 1; }
    if (i1 != 2 && a2 > b2) { b2 = a2; i2 = 2; }
    if (i1 != 3 && a3 > b2) { b2 = a3; i2 = 3; }
    gw[(size_t)b * 4 + 0] = (i1 == 0 || i2 == 0) ? p0 : 0.f;
    gw[(size_t)b * 4 + 1] = (i1 == 1 || i2 == 1) ? p1 : 0.f;
    gw[(size_t)b * 4 + 2] = (i1 == 2 || i2 == 2) ? p2 : 0.f;
    gw[(size_t)b * 4 + 3] = (i1 == 3 || i2 == 3) ? p3 : 0.f;
    // pair code over sorted (lo,hi): (0,1)->0 (0,2)->1 (0,3)->2 (1,2)->3 (1,3)->4 (2,3)->5
    int lo = min(i1, i2), hi = max(i1, i2);
    int code = (lo == 0) ? (hi - 1) : (lo == 1) ? (hi + 1) : 5;
    pair[b] = code;
    atomicAdd(&cnt[code], 1);
  }
}

// ---------------- kernel 2: We [E][F][P] f32 -> We_T [E][P][F] bf16 ----------------
__global__ __launch_bounds__(256) void we_transpose(
    const float* __restrict__ We, unsigned short* __restrict__ WeT)
{
  __shared__ float t[64][65];
  const int e  = blockIdx.z;
  const int tf = blockIdx.x * 64;
  const int tp = blockIdx.y * 64;
  const int t4 = threadIdx.x * 4;
  const float* src = We + ((size_t)e * NF + tf) * NP + tp;
  #pragma unroll
  for (int i = 0; i < 4; ++i) {
    int li = i * 1024 + t4;
    int r = li >> 6, c = li & 63;
    float4 v = *(const float4*)(src + (size_t)r * NP + c);
    t[c][r] = v.x; t[c+1][r] = v.y; t[c+2][r] = v.z; t[c+3][r] = v.w;
  }
  __syncthreads();
  unsigned short* dst = WeT + ((size_t)e * NP + tp) * NF + tf;
  #pragma unroll
  for (int i = 0; i < 4; ++i) {
    int li = i * 1024 + t4;
    int r = li >> 6, c = li & 63;
    ushort4 o;
    o.x = f32_bf16(t[r][c]);   o.y = f32_bf16(t[r][c+1]);
    o.z = f32_bf16(t[r][c+2]); o.w = f32_bf16(t[r][c+3]);
    *(ushort4*)(dst + (size_t)r * NF + c) = o;
  }
}

// ---------------- kernel 3: bucket offsets + tile table (1 thread, trivial) ----------------
__global__ void bucket_setup(const int* __restrict__ cnt, int* __restrict__ cursor,
                             int* __restrict__ ntiles, int4* __restrict__ tiletab)
{
  const int e1t[6] = {0, 0, 0, 1, 1, 2};
  const int e2t[6] = {1, 2, 3, 2, 3, 3};
  int off = 0, nt = 0;
  for (int b = 0; b < 6; ++b) {
    const int c = cnt[b];
    cursor[b] = off;
    for (int i = 0; i < c; i += 128) {
      tiletab[nt] = make_int4(off + i, min(128, c - i), e1t[b], e2t[b]);
      ++nt;
    }
    off += c;
  }
  *ntiles = nt;
}

// ---------------- kernel 4: scatter row ids into buckets ----------------
__global__ __launch_bounds__(256) void bucket_fill(
    const int* __restrict__ pair, int* __restrict__ cursor, int* __restrict__ ridx)
{
  const int r = blockIdx.x * 256 + threadIdx.x;
  const int p = pair[r];
  const int pos = atomicAdd(&cursor[p], 1);
  ridx[pos] = r;
}

// ---------------- kernel 5: sparse top-2 GEMM (r3 structure: depth-2, counted vmcnt) ----------
// Each block: one 128-row bucket tile x one 128-col tile; 64 K-steps (2 experts x 32).
// Row gather via per-lane global_load_lds source address; LDS linear + XOR swizzle (rule #21).
__global__ __launch_bounds__(256, 2) void moe_gemm(
    const unsigned short* __restrict__ fusedB,   // [B][F] bf16
    const unsigned short* __restrict__ WeT,      // [E][P][F] bf16
    const float* __restrict__ gw,                // [B][4]
    const float* __restrict__ be,                // [E][P]
    const float* __restrict__ label,             // [B][P]
    const int* __restrict__ ntilesP,
    const int4* __restrict__ tiletab,
    const int* __restrict__ ridx,
    float* __restrict__ out,                     // [0]=loss, [1..] preds
    double* __restrict__ lossAcc)
{
  if ((int)blockIdx.y >= *ntilesP) return;

  __shared__ __align__(16) unsigned short As[2][128 * 64];
  __shared__ __align__(16) unsigned short Bs[2][128 * 64];
  __shared__ int   ridxS[128];
  __shared__ float gwS[128][2];
  __shared__ float red[4];

  const int4 te     = tiletab[blockIdx.y];
  const int rowbase = te.x;
  const int vcount  = te.y;
  const int e1      = te.z;
  const int e2      = te.w;
  const int pcol    = (int)blockIdx.x * 128;

  const int tid  = threadIdx.x;
  const int l    = tid & 63;
  const int wave = tid >> 6;
  const int wr   = wave >> 1;
  const int wc   = wave & 1;
  const int lrow = l & 15;
  const int g4   = l >> 4;
  const int lr8  = l >> 3;
  const int lc8  = l & 7;
  const int schA = lc8 ^ lr8;   // inverse-swizzled source chunk (r0 is 8-aligned)

  if (tid < 128) {
    const int ri = ridx[rowbase + min(tid, vcount - 1)];  // clamp pads to last valid row
    ridxS[tid]  = ri;
    gwS[tid][0] = gw[(size_t)ri * 4 + e1];
    gwS[tid][1] = gw[(size_t)ri * 4 + e2];
  }
  __syncthreads();

  // per-lane gathered A-row ids for the 4 staging stripes (fixed across K)
  int rowA[4];
  #pragma unroll
  for (int i = 0; i < 4; ++i) rowA[i] = ridxS[wave * 32 + i * 8 + lr8];

  f32x4 accT[4][4], accE[4][4];
  #pragma unroll
  for (int m = 0; m < 4; ++m)
    #pragma unroll
    for (int n = 0; n < 4; ++n) {
      accT[m][n] = f32x4{0.f, 0.f, 0.f, 0.f};
      accE[m][n] = f32x4{0.f, 0.f, 0.f, 0.f};
    }

  // stage flat step t (expert idx = t>>5, k-tile = t&31): 8 GLOAD16 per wave
  auto STAGE = [&](int t, int buf) {
    const int e  = (t >> 5) ? e2 : e1;
    const int k0 = (t & 31) << 6;
    const unsigned short* Bg = WeT + ((size_t)e * NP + pcol) * NF + k0;
    #pragma unroll
    for (int i = 0; i < 4; ++i) {
      const int r0 = wave * 32 + i * 8;
      GLOAD16(fusedB + (size_t)rowA[i] * NF + k0 + schA * 8, (char*)(&As[buf][r0 * 64]));
      GLOAD16(Bg + (size_t)(r0 + lr8) * NF + schA * 8,       (char*)(&Bs[buf][r0 * 64]));
    }
  };

  auto COMPUTE = [&](int buf) {
    #pragma unroll
    for (int ks = 0; ks < 2; ++ks) {
      bf16x8 af[4], bfr[4];
      #pragma unroll
      for (int m = 0; m < 4; ++m) {
        const int fr = wr * 64 + m * 16 + lrow;
        const int ch = ((g4 + ks * 4) ^ (fr & 7)) * 8;
        af[m] = __builtin_bit_cast(bf16x8, *(const u16x8*)(&As[buf][fr * 64 + ch]));
      }
      #pragma unroll
      for (int n = 0; n < 4; ++n) {
        const int fr = wc * 64 + n * 16 + lrow;
        const int ch = ((g4 + ks * 4) ^ (fr & 7)) * 8;
        bfr[n] = __builtin_bit_cast(bf16x8, *(const u16x8*)(&Bs[buf][fr * 64 + ch]));
      }
      #pragma unroll
      for (int m = 0; m < 4; ++m)
        #pragma unroll
        for (int n = 0; n < 4; ++n)
          accE[m][n] = __builtin_amdgcn_mfma_f32_16x16x32_bf16(af[m], bfr[n], accE[m][n], 0, 0, 0);
    }
  };

  auto FOLD = [&](int ei) {   // accT += w[row,ei]*accE; accE = 0 (register-only)
    #pragma unroll
    for (int m = 0; m < 4; ++m)
      #pragma unroll
      for (int r = 0; r < 4; ++r) {
        const float wv = gwS[wr * 64 + m * 16 + g4 * 4 + r][ei];
        #pragma unroll
        for (int n = 0; n < 4; ++n) {
          accT[m][n][r] += wv * accE[m][n][r];
          accE[m][n][r] = 0.f;
        }
      }
  };

  STAGE(0, 0);
  STAGE(1, 1);

  #pragma unroll 1
  for (int t = 0; t < 64; ++t) {
    const int buf = t & 1;
    // outstanding batches at top: {t, t+1} (8 loads each) for t<63; {63} at t=63
    if (t == 63) asm volatile("s_waitcnt vmcnt(0)" ::: "memory");
    else         asm volatile("s_waitcnt vmcnt(8)" ::: "memory");
    __builtin_amdgcn_s_barrier();          // batch-t loads landed for all waves
    COMPUTE(buf);
    if ((t & 31) == 31) FOLD(t >> 5);
    __builtin_amdgcn_sched_barrier(0);     // pin ds_reads+MFMAs before the barrier
    __builtin_amdgcn_s_barrier();          // every wave done reading buf
    if (t < 62) STAGE(t + 2, buf);         // overwrite freed buffer
  }

  // epilogue: bias, masked scatter-store of preds, fused MSE partial
  float lsum = 0.f;
  #pragma unroll
  for (int m = 0; m < 4; ++m) {
    #pragma unroll
    for (int r = 0; r < 4; ++r) {
      const int lrowi = wr * 64 + m * 16 + g4 * 4 + r;
      const bool valid = lrowi < vcount;
      const int grow = ridxS[lrowi];
      const float w1 = gwS[lrowi][0];
      const float w2 = gwS[lrowi][1];
      #pragma unroll
      for (int n = 0; n < 4; ++n) {
        const int gcol = pcol + wc * 64 + n * 16 + lrow;
        float bias = w1 * be[e1 * NP + gcol] + w2 * be[e2 * NP + gcol];
        float pred = accT[m][n][r] + bias;
        if (valid) {
          out[1 + (size_t)grow * NP + gcol] = pred;
          float d = pred - label[(size_t)grow * NP + gcol];
          lsum += d * d;
        }
      }
    }
  }
  #pragma unroll
  for (int off = 32; off; off >>= 1) lsum += __shfl_xor(lsum, off);
  if (l == 0) red[wave] = lsum;
  __syncthreads();
  if (tid == 0) {
    double s = (double)red[0] + (double)red[1] + (double)red[2] + (double)red[3];
    atomicAdd(lossAcc, s);
  }
}

// ---------------- kernel 6: finalize loss ----------------
__global__ void finalize_kernel(const double* __restrict__ lossAcc, float* __restrict__ out) {
  out[0] = (float)(*lossAcc * (1.0 / ((double)Bsz * (double)NP)));
}

extern "C" void kernel_launch(void* const* d_in, const int* in_sizes, int n_in,
                              void* d_out, int out_size, void* d_ws, size_t ws_size,
                              hipStream_t stream) {
  const float* x0    = (const float*)d_in[0];
  const float* x1    = (const float*)d_in[1];
  const float* x2    = (const float*)d_in[2];
  const float* x3    = (const float*)d_in[3];
  const float* label = (const float*)d_in[4];
  const float* Wg    = (const float*)d_in[5];
  const float* We    = (const float*)d_in[6];
  const float* be    = (const float*)d_in[7];
  float* out = (float*)d_out;

  char* ws = (char*)d_ws;
  unsigned short* WeT    = (unsigned short*)ws;                         // 16 MiB
  unsigned short* fusedB = (unsigned short*)(ws + ((size_t)16 << 20));  // 32 MiB
  float*  gw      = (float*)(ws + ((size_t)48 << 20));                  // 128 KiB
  char*   misc    = ws + ((size_t)49 << 20);
  double* lossAcc = (double*)(misc + 0);
  int*    cnt     = (int*)(misc + 64);
  int*    cursor  = (int*)(misc + 128);
  int*    ntiles  = (int*)(misc + 192);
  int4*   tiletab = (int4*)(misc + 256);          // 70 * 16 B
  int*    pair    = (int*)(misc + 4096);          // 32 KiB
  int*    ridx    = (int*)(misc + 4096 + 32768);  // 32 KiB

  init_kernel<<<1, 64, 0, stream>>>(cnt, lossAcc);
  fuse_gate<<<dim3(Bsz), 256, 0, stream>>>(x0, x1, x2, x3, Wg, fusedB, gw, pair, cnt);
  we_transpose<<<dim3(NF / 64, NP / 64, NE), 256, 0, stream>>>(We, WeT);
  bucket_setup<<<1, 1, 0, stream>>>(cnt, cursor, ntiles, tiletab);
  bucket_fill<<<dim3(Bsz / 256), 256, 0, stream>>>(pair, cursor, ridx);
  moe_gemm<<<dim3(NP / 128, MAXTILES), 256, 0, stream>>>(
      fusedB, WeT, gw, be, label, ntiles, tiletab, ridx, out, lossAcc);
  finalize_kernel<<<1, 1, 0, stream>>>(lossAcc, out);
}

// Round 6
// 233.320 us; speedup vs baseline: 1.4146x; 1.4146x over previous
//
#include <hip/hip_runtime.h>
#include <stdint.h>

#define Bsz  8192
#define DMOD 512
#define NE   4
#define NP   1024
#define NF   2048
#define MAXTILES 70   // sum_b ceil(cnt_b/128) <= 8192/128 + 6

typedef float  f32x4  __attribute__((ext_vector_type(4)));
typedef __bf16 bf16x8 __attribute__((ext_vector_type(8)));
typedef unsigned short u16x8 __attribute__((ext_vector_type(8)));

typedef __attribute__((address_space(3))) void       lds_void;
typedef const __attribute__((address_space(1))) void glb_void;
#define GLOAD16(gp, lp) \
  __builtin_amdgcn_global_load_lds((glb_void*)(gp), (lds_void*)(lp), 16, 0, 0)

__device__ __forceinline__ unsigned short f32_bf16(float f) {
  unsigned int u = __float_as_uint(f);
  u += 0x7FFFu + ((u >> 16) & 1u);   // round-to-nearest-even
  return (unsigned short)(u >> 16);
}

// ---------------- kernel 1: gate logits -> softmax -> top2 -> gw + pair code ----------------
__global__ __launch_bounds__(256) void gate_kernel(
    const float* __restrict__ x0, const float* __restrict__ x1,
    const float* __restrict__ x2, const float* __restrict__ x3,
    const float* __restrict__ Wg,
    float* __restrict__ gw, int* __restrict__ pair)
{
  __shared__ float sred[4][4];
  const int b   = blockIdx.x;
  const int tid = threadIdx.x;
  const int f   = tid * 8;
  const float* xm  = (f < 1024) ? (f < 512 ? x0 : x1) : (f < 1536 ? x2 : x3);
  const float* src = xm + (size_t)b * DMOD + (f & 511);
  float4 v0 = *(const float4*)src;
  float4 v1 = *(const float4*)(src + 4);

  float d[4];
  #pragma unroll
  for (int e = 0; e < 4; ++e) {
    const float* w = Wg + e * NF + f;
    d[e] = v0.x * w[0] + v0.y * w[1] + v0.z * w[2] + v0.w * w[3]
         + v1.x * w[4] + v1.y * w[5] + v1.z * w[6] + v1.w * w[7];
  }
  #pragma unroll
  for (int off = 32; off; off >>= 1) {
    #pragma unroll
    for (int e = 0; e < 4; ++e) d[e] += __shfl_xor(d[e], off);
  }
  if ((tid & 63) == 0) {
    #pragma unroll
    for (int e = 0; e < 4; ++e) sred[tid >> 6][e] = d[e];
  }
  __syncthreads();
  if (tid == 0) {
    float a0 = sred[0][0] + sred[1][0] + sred[2][0] + sred[3][0];
    float a1 = sred[0][1] + sred[1][1] + sred[2][1] + sred[3][1];
    float a2 = sred[0][2] + sred[1][2] + sred[2][2] + sred[3][2];
    float a3 = sred[0][3] + sred[1][3] + sred[2][3] + sred[3][3];
    float m  = fmaxf(fmaxf(a0, a1), fmaxf(a2, a3));
    float e0 = expf(a0 - m), e1 = expf(a1 - m), e2 = expf(a2 - m), e3 = expf(a3 - m);
    float inv = 1.f / (e0 + e1 + e2 + e3);
    float p0 = e0 * inv, p1 = e1 * inv, p2 = e2 * inv, p3 = e3 * inv;
    // top-2, jax tie-break (lower index wins -> strict >)
    int i1 = 0; float b1 = a0;
    if (a1 > b1) { b1 = a1; i1 = 1; }
    if (a2 > b1) { b1 = a2; i1 = 2; }
    if (a3 > b1) { b1 = a3; i1 = 3; }
    int i2 = -1; float b2 = -3.4e38f;
    if (i1 != 0 && a0 > b2) { b2 = a0; i2 = 0; }
    if (i1 != 1 && a1 > b2) { b2 = a1; i2 = 1; }
    if (i1 != 2 && a2 > b2) { b2 = a2; i2 = 2; }
    if (i1 != 3 && a3 > b2) { b2 = a3; i2 = 3; }
    gw[(size_t)b * 4 + 0] = (i1 == 0 || i2 == 0) ? p0 : 0.f;
    gw[(size_t)b * 4 + 1] = (i1 == 1 || i2 == 1) ? p1 : 0.f;
    gw[(size_t)b * 4 + 2] = (i1 == 2 || i2 == 2) ? p2 : 0.f;
    gw[(size_t)b * 4 + 3] = (i1 == 3 || i2 == 3) ? p3 : 0.f;
    // pair code over sorted (lo,hi): (0,1)->0 (0,2)->1 (0,3)->2 (1,2)->3 (1,3)->4 (2,3)->5
    int lo = min(i1, i2), hi = max(i1, i2);
    pair[b] = (lo == 0) ? (hi - 1) : (lo == 1) ? (hi + 1) : 5;
  }
}

// ---------------- kernel 2: We [E][F][P] f32 -> We_T [E][P][F] bf16 ----------------
__global__ __launch_bounds__(256) void we_transpose(
    const float* __restrict__ We, unsigned short* __restrict__ WeT)
{
  __shared__ float t[64][65];
  const int e  = blockIdx.z;
  const int tf = blockIdx.x * 64;
  const int tp = blockIdx.y * 64;
  const int t4 = threadIdx.x * 4;
  const float* src = We + ((size_t)e * NF + tf) * NP + tp;
  #pragma unroll
  for (int i = 0; i < 4; ++i) {
    int li = i * 1024 + t4;
    int r = li >> 6, c = li & 63;
    float4 v = *(const float4*)(src + (size_t)r * NP + c);
    t[c][r] = v.x; t[c+1][r] = v.y; t[c+2][r] = v.z; t[c+3][r] = v.w;
  }
  __syncthreads();
  unsigned short* dst = WeT + ((size_t)e * NP + tp) * NF + tf;
  #pragma unroll
  for (int i = 0; i < 4; ++i) {
    int li = i * 1024 + t4;
    int r = li >> 6, c = li & 63;
    ushort4 o;
    o.x = f32_bf16(t[r][c]);   o.y = f32_bf16(t[r][c+1]);
    o.z = f32_bf16(t[r][c+2]); o.w = f32_bf16(t[r][c+3]);
    *(ushort4*)(dst + (size_t)r * NF + c) = o;
  }
}

// ---------------- kernel 3: deterministic single-block bucket scan ----------------
// 256 threads x 32 rows each: LDS histogram + exclusive scan + stable placement.
// No global atomics, no 1-thread serial global chains (r5's prologue bugs).
__global__ __launch_bounds__(256) void bucket_scan(
    const int* __restrict__ pair, int* __restrict__ ridx,
    int4* __restrict__ tiletab, int* __restrict__ ntiles,
    double* __restrict__ lossAcc)
{
  __shared__ int cntS[256][6];
  __shared__ int baseS[6];
  const int tid = threadIdx.x;
  int c[6] = {0, 0, 0, 0, 0, 0};
  for (int i = 0; i < 32; ++i) {
    const int code = pair[tid * 32 + i];
    #pragma unroll
    for (int b = 0; b < 6; ++b) c[b] += (code == b) ? 1 : 0;   // static idx (rule #20)
  }
  #pragma unroll
  for (int b = 0; b < 6; ++b) cntS[tid][b] = c[b];
  __syncthreads();
  if (tid < 6) {                 // exclusive scan over 256 per-thread counts
    int run = 0;
    for (int i = 0; i < 256; ++i) { const int v = cntS[i][tid]; cntS[i][tid] = run; run += v; }
    baseS[tid] = run;            // bucket total (temporarily)
  }
  __syncthreads();
  if (tid == 0) {
    const int e1t[6] = {0, 0, 0, 1, 1, 2};
    const int e2t[6] = {1, 2, 3, 2, 3, 3};
    int base[6];
    int off = 0, nt = 0;
    for (int b = 0; b < 6; ++b) {
      base[b] = off;
      const int cb = baseS[b];
      for (int i = 0; i < cb; i += 128)
        tiletab[nt++] = make_int4(off + i, min(128, cb - i), e1t[b], e2t[b]);
      off += cb;
    }
    *ntiles = nt;
    *lossAcc = 0.0;
    #pragma unroll
    for (int b = 0; b < 6; ++b) baseS[b] = base[b];
  }
  __syncthreads();
  int pos[6];
  #pragma unroll
  for (int b = 0; b < 6; ++b) pos[b] = baseS[b] + cntS[tid][b];
  for (int i = 0; i < 32; ++i) {
    const int r = tid * 32 + i;
    const int code = pair[r];
    #pragma unroll
    for (int b = 0; b < 6; ++b)
      if (code == b) { ridx[pos[b]] = r; ++pos[b]; }
  }
}

// ---------------- kernel 4: gather + concat + cvt: fusedP[pos] = bf16(x[ridx[pos]]) --------
__global__ __launch_bounds__(256) void permute_cvt(
    const float* __restrict__ x0, const float* __restrict__ x1,
    const float* __restrict__ x2, const float* __restrict__ x3,
    const int* __restrict__ ridx, unsigned short* __restrict__ fusedP)
{
  const int pos = blockIdx.x;
  const int r   = ridx[pos];
  const int tid = threadIdx.x;
  const int f   = tid * 8;
  const float* xm  = (f < 1024) ? (f < 512 ? x0 : x1) : (f < 1536 ? x2 : x3);
  const float* src = xm + (size_t)r * DMOD + (f & 511);
  float4 v0 = *(const float4*)src;
  float4 v1 = *(const float4*)(src + 4);
  u16x8 o;
  o[0] = f32_bf16(v0.x); o[1] = f32_bf16(v0.y); o[2] = f32_bf16(v0.z); o[3] = f32_bf16(v0.w);
  o[4] = f32_bf16(v1.x); o[5] = f32_bf16(v1.y); o[6] = f32_bf16(v1.z); o[7] = f32_bf16(v1.w);
  *(u16x8*)(fusedP + (size_t)pos * NF + f) = o;
}

// ---------------- kernel 5: sparse top-2 GEMM over bucket-ordered rows (r3 structure) -------
// Contiguous A rows (fusedP), depth-2 LDS dbuf, counted vmcnt(8), raw s_barrier,
// XOR-swizzled LDS via inverse-swizzled global source, 64 K-steps (2 experts).
__global__ __launch_bounds__(256, 2) void moe_gemm(
    const unsigned short* __restrict__ fusedP,   // [B][F] bf16, bucket order
    const unsigned short* __restrict__ WeT,      // [E][P][F] bf16
    const float* __restrict__ gw,                // [B][4] (original row order)
    const float* __restrict__ be,                // [E][P]
    const float* __restrict__ label,             // [B][P]
    const int* __restrict__ ntilesP,
    const int4* __restrict__ tiletab,
    const int* __restrict__ ridx,
    float* __restrict__ out,                     // [0]=loss, [1..] preds
    double* __restrict__ lossAcc)
{
  // XCD-chunked 1D swizzle: 560 = 70*8, XCD c gets swz [c*70, c*70+70) = ~9 tiles.
  const int bid  = (int)blockIdx.x;
  const int swz  = (bid & 7) * 70 + (bid >> 3);
  const int tile = swz >> 3;
  if (tile >= *ntilesP) return;
  const int pcol = (swz & 7) * 128;

  __shared__ __align__(16) unsigned short As[2][128 * 64];
  __shared__ __align__(16) unsigned short Bs[2][128 * 64];
  __shared__ int   ridxS[128];
  __shared__ float gwS[128][2];
  __shared__ float red[4];

  const int4 te     = tiletab[tile];
  const int rowbase = te.x;
  const int vcount  = te.y;
  const int e1      = te.z;
  const int e2      = te.w;

  const int tid  = threadIdx.x;
  const int l    = tid & 63;
  const int wave = tid >> 6;
  const int wr   = wave >> 1;
  const int wc   = wave & 1;
  const int lrow = l & 15;
  const int g4   = l >> 4;
  const int lr8  = l >> 3;
  const int lc8  = l & 7;
  const int schA = lc8 ^ lr8;   // inverse-swizzled source chunk (stripe base 8-aligned)

  if (tid < 128) {
    const int ri = ridx[rowbase + min(tid, vcount - 1)];
    ridxS[tid]  = ri;
    gwS[tid][0] = gw[(size_t)ri * 4 + e1];
    gwS[tid][1] = gw[(size_t)ri * 4 + e2];
  }
  __syncthreads();

  // clamped contiguous A rows for this lane's 4 staging stripes (fixed across K)
  int rowA[4];
  #pragma unroll
  for (int i = 0; i < 4; ++i)
    rowA[i] = rowbase + min(wave * 32 + i * 8 + lr8, vcount - 1);

  f32x4 accT[4][4], accE[4][4];
  #pragma unroll
  for (int m = 0; m < 4; ++m)
    #pragma unroll
    for (int n = 0; n < 4; ++n) {
      accT[m][n] = f32x4{0.f, 0.f, 0.f, 0.f};
      accE[m][n] = f32x4{0.f, 0.f, 0.f, 0.f};
    }

  auto STAGE = [&](int t, int buf) {
    const int e  = (t >> 5) ? e2 : e1;
    const int k0 = (t & 31) << 6;
    const unsigned short* Bg = WeT + ((size_t)e * NP + pcol) * NF + k0;
    #pragma unroll
    for (int i = 0; i < 4; ++i) {
      const int r0 = wave * 32 + i * 8;
      GLOAD16(fusedP + (size_t)rowA[i] * NF + k0 + schA * 8, (char*)(&As[buf][r0 * 64]));
      GLOAD16(Bg + (size_t)(r0 + lr8) * NF + schA * 8,       (char*)(&Bs[buf][r0 * 64]));
    }
  };

  auto COMPUTE = [&](int buf) {
    #pragma unroll
    for (int ks = 0; ks < 2; ++ks) {
      bf16x8 af[4], bfr[4];
      #pragma unroll
      for (int m = 0; m < 4; ++m) {
        const int fr = wr * 64 + m * 16 + lrow;
        const int ch = ((g4 + ks * 4) ^ (fr & 7)) * 8;
        af[m] = __builtin_bit_cast(bf16x8, *(const u16x8*)(&As[buf][fr * 64 + ch]));
      }
      #pragma unroll
      for (int n = 0; n < 4; ++n) {
        const int fr = wc * 64 + n * 16 + lrow;
        const int ch = ((g4 + ks * 4) ^ (fr & 7)) * 8;
        bfr[n] = __builtin_bit_cast(bf16x8, *(const u16x8*)(&Bs[buf][fr * 64 + ch]));
      }
      #pragma unroll
      for (int m = 0; m < 4; ++m)
        #pragma unroll
        for (int n = 0; n < 4; ++n)
          accE[m][n] = __builtin_amdgcn_mfma_f32_16x16x32_bf16(af[m], bfr[n], accE[m][n], 0, 0, 0);
    }
  };

  auto FOLD = [&](int ei) {   // accT += w[row,ei]*accE; accE = 0 (register-only)
    #pragma unroll
    for (int m = 0; m < 4; ++m)
      #pragma unroll
      for (int r = 0; r < 4; ++r) {
        const float wv = gwS[wr * 64 + m * 16 + g4 * 4 + r][ei];
        #pragma unroll
        for (int n = 0; n < 4; ++n) {
          accT[m][n][r] += wv * accE[m][n][r];
          accE[m][n][r] = 0.f;
        }
      }
  };

  STAGE(0, 0);
  STAGE(1, 1);

  #pragma unroll 1
  for (int t = 0; t < 64; ++t) {
    const int buf = t & 1;
    // outstanding at top: batches {t, t+1} (8 loads each) for t<63; {63} at t=63
    if (t == 63) asm volatile("s_waitcnt vmcnt(0)" ::: "memory");
    else         asm volatile("s_waitcnt vmcnt(8)" ::: "memory");
    __builtin_amdgcn_s_barrier();          // batch-t loads landed for all waves
    COMPUTE(buf);
    if ((t & 31) == 31) FOLD(t >> 5);
    __builtin_amdgcn_sched_barrier(0);     // pin ds_reads+MFMAs before the barrier
    __builtin_amdgcn_s_barrier();          // every wave done reading buf
    if (t < 62) STAGE(t + 2, buf);         // overwrite freed buffer
  }

  // epilogue: bias, masked scatter-store of preds, fused MSE partial
  float lsum = 0.f;
  #pragma unroll
  for (int m = 0; m < 4; ++m) {
    #pragma unroll
    for (int r = 0; r < 4; ++r) {
      const int lrowi = wr * 64 + m * 16 + g4 * 4 + r;
      const bool valid = lrowi < vcount;
      const int grow = ridxS[lrowi];
      const float w1 = gwS[lrowi][0];
      const float w2 = gwS[lrowi][1];
      #pragma unroll
      for (int n = 0; n < 4; ++n) {
        const int gcol = pcol + wc * 64 + n * 16 + lrow;
        float bias = w1 * be[e1 * NP + gcol] + w2 * be[e2 * NP + gcol];
        float pred = accT[m][n][r] + bias;
        if (valid) {
          out[1 + (size_t)grow * NP + gcol] = pred;
          float d = pred - label[(size_t)grow * NP + gcol];
          lsum += d * d;
        }
      }
    }
  }
  #pragma unroll
  for (int off = 32; off; off >>= 1) lsum += __shfl_xor(lsum, off);
  if (l == 0) red[wave] = lsum;
  __syncthreads();
  if (tid == 0) {
    double s = (double)red[0] + (double)red[1] + (double)red[2] + (double)red[3];
    atomicAdd(lossAcc, s);
  }
}

// ---------------- kernel 6: finalize loss ----------------
__global__ void finalize_kernel(const double* __restrict__ lossAcc, float* __restrict__ out) {
  out[0] = (float)(*lossAcc * (1.0 / ((double)Bsz * (double)NP)));
}

extern "C" void kernel_launch(void* const* d_in, const int* in_sizes, int n_in,
                              void* d_out, int out_size, void* d_ws, size_t ws_size,
                              hipStream_t stream) {
  const float* x0    = (const float*)d_in[0];
  const float* x1    = (const float*)d_in[1];
  const float* x2    = (const float*)d_in[2];
  const float* x3    = (const float*)d_in[3];
  const float* label = (const float*)d_in[4];
  const float* Wg    = (const float*)d_in[5];
  const float* We    = (const float*)d_in[6];
  const float* be    = (const float*)d_in[7];
  float* out = (float*)d_out;

  char* ws = (char*)d_ws;
  unsigned short* WeT    = (unsigned short*)ws;                         // 16 MiB
  unsigned short* fusedP = (unsigned short*)(ws + ((size_t)16 << 20));  // 32 MiB
  float*  gw      = (float*)(ws + ((size_t)48 << 20));                  // 128 KiB
  char*   misc    = ws + ((size_t)49 << 20);
  double* lossAcc = (double*)(misc + 0);
  int*    ntiles  = (int*)(misc + 64);
  int4*   tiletab = (int4*)(misc + 256);          // 70 * 16 B
  int*    pair    = (int*)(misc + 4096);          // 32 KiB
  int*    ridx    = (int*)(misc + 4096 + 32768);  // 32 KiB

  gate_kernel<<<dim3(Bsz), 256, 0, stream>>>(x0, x1, x2, x3, Wg, gw, pair);
  bucket_scan<<<dim3(1), 256, 0, stream>>>(pair, ridx, tiletab, ntiles, lossAcc);
  permute_cvt<<<dim3(Bsz), 256, 0, stream>>>(x0, x1, x2, x3, ridx, fusedP);
  we_transpose<<<dim3(NF / 64, NP / 64, NE), 256, 0, stream>>>(We, WeT);
  moe_gemm<<<dim3(MAXTILES * 8), 256, 0, stream>>>(
      fusedP, WeT, gw, be, label, ntiles, tiletab, ridx, out, lossAcc);
  finalize_kernel<<<1, 1, 0, stream>>>(lossAcc, out);
}

// Round 7
// 170.959 us; speedup vs baseline: 1.9306x; 1.3648x over previous
//
#include <hip/hip_runtime.h>
#include <stdint.h>

#define Bsz  8192
#define DMOD 512
#define NE   4
#define NP   1024
#define NF   2048
#define BM   160
#define MAXTILES 57   // sum_b ceil(cnt_b/160) <= ceil(8192/160)+5 = 57

typedef float  f32x4  __attribute__((ext_vector_type(4)));
typedef __bf16 bf16x8 __attribute__((ext_vector_type(8)));
typedef unsigned short u16x8 __attribute__((ext_vector_type(8)));

typedef __attribute__((address_space(3))) void       lds_void;
typedef const __attribute__((address_space(1))) void glb_void;
#define GLOAD16(gp, lp) \
  __builtin_amdgcn_global_load_lds((glb_void*)(gp), (lds_void*)(lp), 16, 0, 0)

__device__ __forceinline__ unsigned short f32_bf16(float f) {
  unsigned int u = __float_as_uint(f);
  u += 0x7FFFu + ((u >> 16) & 1u);   // round-to-nearest-even
  return (unsigned short)(u >> 16);
}

// ---------------- kernel 1: gate logits -> softmax -> top2 -> gw + pair code ----------------
__global__ __launch_bounds__(256) void gate_kernel(
    const float* __restrict__ x0, const float* __restrict__ x1,
    const float* __restrict__ x2, const float* __restrict__ x3,
    const float* __restrict__ Wg,
    float* __restrict__ gw, int* __restrict__ pair)
{
  __shared__ float sred[4][4];
  const int b   = blockIdx.x;
  const int tid = threadIdx.x;
  const int f   = tid * 8;
  const float* xm  = (f < 1024) ? (f < 512 ? x0 : x1) : (f < 1536 ? x2 : x3);
  const float* src = xm + (size_t)b * DMOD + (f & 511);
  float4 v0 = *(const float4*)src;
  float4 v1 = *(const float4*)(src + 4);

  float d[4];
  #pragma unroll
  for (int e = 0; e < 4; ++e) {
    const float* w = Wg + e * NF + f;
    d[e] = v0.x * w[0] + v0.y * w[1] + v0.z * w[2] + v0.w * w[3]
         + v1.x * w[4] + v1.y * w[5] + v1.z * w[6] + v1.w * w[7];
  }
  #pragma unroll
  for (int off = 32; off; off >>= 1) {
    #pragma unroll
    for (int e = 0; e < 4; ++e) d[e] += __shfl_xor(d[e], off);
  }
  if ((tid & 63) == 0) {
    #pragma unroll
    for (int e = 0; e < 4; ++e) sred[tid >> 6][e] = d[e];
  }
  __syncthreads();
  if (tid == 0) {
    float a0 = sred[0][0] + sred[1][0] + sred[2][0] + sred[3][0];
    float a1 = sred[0][1] + sred[1][1] + sred[2][1] + sred[3][1];
    float a2 = sred[0][2] + sred[1][2] + sred[2][2] + sred[3][2];
    float a3 = sred[0][3] + sred[1][3] + sred[2][3] + sred[3][3];
    float m  = fmaxf(fmaxf(a0, a1), fmaxf(a2, a3));
    float e0 = expf(a0 - m), e1 = expf(a1 - m), e2 = expf(a2 - m), e3 = expf(a3 - m);
    float inv = 1.f / (e0 + e1 + e2 + e3);
    float p0 = e0 * inv, p1 = e1 * inv, p2 = e2 * inv, p3 = e3 * inv;
    // top-2, jax tie-break (lower index wins -> strict >)
    int i1 = 0; float b1 = a0;
    if (a1 > b1) { b1 = a1; i1 = 1; }
    if (a2 > b1) { b1 = a2; i1 = 2; }
    if (a3 > b1) { b1 = a3; i1 = 3; }
    int i2 = -1; float b2 = -3.4e38f;
    if (i1 != 0 && a0 > b2) { b2 = a0; i2 = 0; }
    if (i1 != 1 && a1 > b2) { b2 = a1; i2 = 1; }
    if (i1 != 2 && a2 > b2) { b2 = a2; i2 = 2; }
    if (i1 != 3 && a3 > b2) { b2 = a3; i2 = 3; }
    gw[(size_t)b * 4 + 0] = (i1 == 0 || i2 == 0) ? p0 : 0.f;
    gw[(size_t)b * 4 + 1] = (i1 == 1 || i2 == 1) ? p1 : 0.f;
    gw[(size_t)b * 4 + 2] = (i1 == 2 || i2 == 2) ? p2 : 0.f;
    gw[(size_t)b * 4 + 3] = (i1 == 3 || i2 == 3) ? p3 : 0.f;
    // pair code over sorted (lo,hi): (0,1)->0 (0,2)->1 (0,3)->2 (1,2)->3 (1,3)->4 (2,3)->5
    int lo = min(i1, i2), hi = max(i1, i2);
    pair[b] = (lo == 0) ? (hi - 1) : (lo == 1) ? (hi + 1) : 5;
  }
}

// ---------------- kernel 2: We [E][F][P] f32 -> We_T [E][P][F] bf16 ----------------
__global__ __launch_bounds__(256) void we_transpose(
    const float* __restrict__ We, unsigned short* __restrict__ WeT)
{
  __shared__ float t[64][65];
  const int e  = blockIdx.z;
  const int tf = blockIdx.x * 64;
  const int tp = blockIdx.y * 64;
  const int t4 = threadIdx.x * 4;
  const float* src = We + ((size_t)e * NF + tf) * NP + tp;
  #pragma unroll
  for (int i = 0; i < 4; ++i) {
    int li = i * 1024 + t4;
    int r = li >> 6, c = li & 63;
    float4 v = *(const float4*)(src + (size_t)r * NP + c);
    t[c][r] = v.x; t[c+1][r] = v.y; t[c+2][r] = v.z; t[c+3][r] = v.w;
  }
  __syncthreads();
  unsigned short* dst = WeT + ((size_t)e * NP + tp) * NF + tf;
  #pragma unroll
  for (int i = 0; i < 4; ++i) {
    int li = i * 1024 + t4;
    int r = li >> 6, c = li & 63;
    ushort4 o;
    o.x = f32_bf16(t[r][c]);   o.y = f32_bf16(t[r][c+1]);
    o.z = f32_bf16(t[r][c+2]); o.w = f32_bf16(t[r][c+3]);
    *(ushort4*)(dst + (size_t)r * NF + c) = o;
  }
}

// ---------------- kernel 3: deterministic single-block bucket scan (BM=160 tiles) ----------
__global__ __launch_bounds__(256) void bucket_scan(
    const int* __restrict__ pair, int* __restrict__ ridx,
    int4* __restrict__ tiletab, int* __restrict__ ntiles,
    double* __restrict__ lossAcc)
{
  __shared__ int cntS[256][6];
  __shared__ int baseS[6];
  const int tid = threadIdx.x;
  int c[6] = {0, 0, 0, 0, 0, 0};
  for (int i = 0; i < 32; ++i) {
    const int code = pair[tid * 32 + i];
    #pragma unroll
    for (int b = 0; b < 6; ++b) c[b] += (code == b) ? 1 : 0;   // static idx (rule #20)
  }
  #pragma unroll
  for (int b = 0; b < 6; ++b) cntS[tid][b] = c[b];
  __syncthreads();
  if (tid < 6) {                 // exclusive scan over 256 per-thread counts
    int run = 0;
    for (int i = 0; i < 256; ++i) { const int v = cntS[i][tid]; cntS[i][tid] = run; run += v; }
    baseS[tid] = run;            // bucket total (temporarily)
  }
  __syncthreads();
  if (tid == 0) {
    const int e1t[6] = {0, 0, 0, 1, 1, 2};
    const int e2t[6] = {1, 2, 3, 2, 3, 3};
    int base[6];
    int off = 0, nt = 0;
    for (int b = 0; b < 6; ++b) {
      base[b] = off;
      const int cb = baseS[b];
      for (int i = 0; i < cb; i += BM)
        tiletab[nt++] = make_int4(off + i, min(BM, cb - i), e1t[b], e2t[b]);
      off += cb;
    }
    *ntiles = nt;
    *lossAcc = 0.0;
    #pragma unroll
    for (int b = 0; b < 6; ++b) baseS[b] = base[b];
  }
  __syncthreads();
  int pos[6];
  #pragma unroll
  for (int b = 0; b < 6; ++b) pos[b] = baseS[b] + cntS[tid][b];
  for (int i = 0; i < 32; ++i) {
    const int r = tid * 32 + i;
    const int code = pair[r];
    #pragma unroll
    for (int b = 0; b < 6; ++b)
      if (code == b) { ridx[pos[b]] = r; ++pos[b]; }
  }
}

// ---------------- kernel 4: gather + concat + cvt: fusedP[pos] = bf16(x[ridx[pos]]) --------
__global__ __launch_bounds__(256) void permute_cvt(
    const float* __restrict__ x0, const float* __restrict__ x1,
    const float* __restrict__ x2, const float* __restrict__ x3,
    const int* __restrict__ ridx, unsigned short* __restrict__ fusedP)
{
  const int pos = blockIdx.x;
  const int r   = ridx[pos];
  const int tid = threadIdx.x;
  const int f   = tid * 8;
  const float* xm  = (f < 1024) ? (f < 512 ? x0 : x1) : (f < 1536 ? x2 : x3);
  const float* src = xm + (size_t)r * DMOD + (f & 511);
  float4 v0 = *(const float4*)src;
  float4 v1 = *(const float4*)(src + 4);
  u16x8 o;
  o[0] = f32_bf16(v0.x); o[1] = f32_bf16(v0.y); o[2] = f32_bf16(v0.z); o[3] = f32_bf16(v0.w);
  o[4] = f32_bf16(v1.x); o[5] = f32_bf16(v1.y); o[6] = f32_bf16(v1.z); o[7] = f32_bf16(v1.w);
  *(u16x8*)(fusedP + (size_t)pos * NF + f) = o;
}

// ---------------- kernel 5: sparse top-2 GEMM, BM=160 tiles (<=456 blocks, no tail) --------
// r6 structure: depth-2 LDS dbuf, counted vmcnt(9), raw s_barrier, XOR-swizzled LDS via
// inverse-swizzled global source. Per wave: 80x64 output (5 m-frags), 64 K-steps.
__global__ __launch_bounds__(256, 2) void moe_gemm(
    const unsigned short* __restrict__ fusedP,   // [B][F] bf16, bucket order
    const unsigned short* __restrict__ WeT,      // [E][P][F] bf16
    const float* __restrict__ gw,                // [B][4] (original row order)
    const float* __restrict__ be,                // [E][P]
    const float* __restrict__ label,             // [B][P]
    const int* __restrict__ ntilesP,
    const int4* __restrict__ tiletab,
    const int* __restrict__ ridx,
    float* __restrict__ out,                     // [0]=loss, [1..] preds
    double* __restrict__ lossAcc)
{
  // XCD-chunked 1D swizzle over 456 = 8*57 blocks: XCD c gets swz [c*57, (c+1)*57).
  const int bid  = (int)blockIdx.x;
  const int swz  = (bid & 7) * 57 + (bid >> 3);
  const int tile = swz >> 3;
  if (tile >= *ntilesP) return;
  const int pcol = (swz & 7) * 128;

  __shared__ __align__(16) unsigned short As[2][BM * 64];   // 40 KiB
  __shared__ __align__(16) unsigned short Bs[2][128 * 64];  // 32 KiB
  __shared__ int   ridxS[BM];
  __shared__ float gwS[BM][2];
  __shared__ float red[4];

  const int4 te     = tiletab[tile];
  const int rowbase = te.x;
  const int vcount  = te.y;
  const int e1      = te.z;
  const int e2      = te.w;

  const int tid  = threadIdx.x;
  const int l    = tid & 63;
  const int wave = tid >> 6;
  const int wr   = wave >> 1;     // 0..1 : rows [wr*80, wr*80+80)
  const int wc   = wave & 1;      // 0..1 : cols [wc*64, wc*64+64)
  const int lrow = l & 15;
  const int g4   = l >> 4;
  const int lr8  = l >> 3;
  const int lc8  = l & 7;
  const int schA = lc8 ^ lr8;     // inverse-swizzled source chunk (stripe base 8-aligned)

  if (tid < BM) {
    const int ri = ridx[rowbase + min(tid, vcount - 1)];
    ridxS[tid]  = ri;
    gwS[tid][0] = gw[(size_t)ri * 4 + e1];
    gwS[tid][1] = gw[(size_t)ri * 4 + e2];
  }
  __syncthreads();

  // clamped contiguous A rows for this lane's 5 staging stripes (8 rows each)
  int rowA[5];
  #pragma unroll
  for (int i = 0; i < 5; ++i)
    rowA[i] = rowbase + min(wave * 40 + i * 8 + lr8, vcount - 1);

  f32x4 accT[5][4], accE[5][4];
  #pragma unroll
  for (int m = 0; m < 5; ++m)
    #pragma unroll
    for (int n = 0; n < 4; ++n) {
      accT[m][n] = f32x4{0.f, 0.f, 0.f, 0.f};
      accE[m][n] = f32x4{0.f, 0.f, 0.f, 0.f};
    }

  // stage flat step t (expert = t>>5, k-tile = t&31): 9 GLOAD16 per wave (5 A + 4 B)
  auto STAGE = [&](int t, int buf) {
    const int e  = (t >> 5) ? e2 : e1;
    const int k0 = (t & 31) << 6;
    const unsigned short* Bg = WeT + ((size_t)e * NP + pcol) * NF + k0;
    #pragma unroll
    for (int i = 0; i < 5; ++i) {
      const int r0 = wave * 40 + i * 8;
      GLOAD16(fusedP + (size_t)rowA[i] * NF + k0 + schA * 8, (char*)(&As[buf][r0 * 64]));
    }
    #pragma unroll
    for (int i = 0; i < 4; ++i) {
      const int r0 = wave * 32 + i * 8;
      GLOAD16(Bg + (size_t)(r0 + lr8) * NF + schA * 8, (char*)(&Bs[buf][r0 * 64]));
    }
  };

  auto COMPUTE = [&](int buf) {
    #pragma unroll
    for (int ks = 0; ks < 2; ++ks) {
      bf16x8 af[5], bfr[4];
      #pragma unroll
      for (int m = 0; m < 5; ++m) {
        const int fr = wr * 80 + m * 16 + lrow;
        const int ch = ((g4 + ks * 4) ^ (fr & 7)) * 8;
        af[m] = __builtin_bit_cast(bf16x8, *(const u16x8*)(&As[buf][fr * 64 + ch]));
      }
      #pragma unroll
      for (int n = 0; n < 4; ++n) {
        const int fr = wc * 64 + n * 16 + lrow;
        const int ch = ((g4 + ks * 4) ^ (fr & 7)) * 8;
        bfr[n] = __builtin_bit_cast(bf16x8, *(const u16x8*)(&Bs[buf][fr * 64 + ch]));
      }
      #pragma unroll
      for (int m = 0; m < 5; ++m)
        #pragma unroll
        for (int n = 0; n < 4; ++n)
          accE[m][n] = __builtin_amdgcn_mfma_f32_16x16x32_bf16(af[m], bfr[n], accE[m][n], 0, 0, 0);
    }
  };

  auto FOLD = [&](int ei) {   // accT += w[row,ei]*accE; accE = 0 (register-only)
    #pragma unroll
    for (int m = 0; m < 5; ++m)
      #pragma unroll
      for (int r = 0; r < 4; ++r) {
        const float wv = gwS[wr * 80 + m * 16 + g4 * 4 + r][ei];
        #pragma unroll
        for (int n = 0; n < 4; ++n) {
          accT[m][n][r] += wv * accE[m][n][r];
          accE[m][n][r] = 0.f;
        }
      }
  };

  STAGE(0, 0);
  STAGE(1, 1);

  #pragma unroll 1
  for (int t = 0; t < 64; ++t) {
    const int buf = t & 1;
    // outstanding at top: batches {t, t+1} (9 loads each) for t<63; {63} at t=63
    if (t == 63) asm volatile("s_waitcnt vmcnt(0)" ::: "memory");
    else         asm volatile("s_waitcnt vmcnt(9)" ::: "memory");
    __builtin_amdgcn_s_barrier();          // batch-t loads landed for all waves
    COMPUTE(buf);
    if ((t & 31) == 31) FOLD(t >> 5);
    __builtin_amdgcn_sched_barrier(0);     // pin ds_reads+MFMAs before the barrier
    __builtin_amdgcn_s_barrier();          // every wave done reading buf
    if (t < 62) STAGE(t + 2, buf);         // overwrite freed buffer
  }

  // epilogue: bias, masked scatter-store of preds, fused MSE partial
  float lsum = 0.f;
  #pragma unroll
  for (int m = 0; m < 5; ++m) {
    #pragma unroll
    for (int r = 0; r < 4; ++r) {
      const int lrowi = wr * 80 + m * 16 + g4 * 4 + r;
      const bool valid = lrowi < vcount;
      const int grow = ridxS[lrowi];
      const float w1 = gwS[lrowi][0];
      const float w2 = gwS[lrowi][1];
      #pragma unroll
      for (int n = 0; n < 4; ++n) {
        const int gcol = pcol + wc * 64 + n * 16 + lrow;
        float bias = w1 * be[e1 * NP + gcol] + w2 * be[e2 * NP + gcol];
        float pred = accT[m][n][r] + bias;
        if (valid) {
          out[1 + (size_t)grow * NP + gcol] = pred;
          float d = pred - label[(size_t)grow * NP + gcol];
          lsum += d * d;
        }
      }
    }
  }
  #pragma unroll
  for (int off = 32; off; off >>= 1) lsum += __shfl_xor(lsum, off);
  if (l == 0) red[wave] = lsum;
  __syncthreads();
  if (tid == 0) {
    double s = (double)red[0] + (double)red[1] + (double)red[2] + (double)red[3];
    atomicAdd(lossAcc, s);
  }
}

// ---------------- kernel 6: finalize loss ----------------
__global__ void finalize_kernel(const double* __restrict__ lossAcc, float* __restrict__ out) {
  out[0] = (float)(*lossAcc * (1.0 / ((double)Bsz * (double)NP)));
}

extern "C" void kernel_launch(void* const* d_in, const int* in_sizes, int n_in,
                              void* d_out, int out_size, void* d_ws, size_t ws_size,
                              hipStream_t stream) {
  const float* x0    = (const float*)d_in[0];
  const float* x1    = (const float*)d_in[1];
  const float* x2    = (const float*)d_in[2];
  const float* x3    = (const float*)d_in[3];
  const float* label = (const float*)d_in[4];
  const float* Wg    = (const float*)d_in[5];
  const float* We    = (const float*)d_in[6];
  const float* be    = (const float*)d_in[7];
  float* out = (float*)d_out;

  char* ws = (char*)d_ws;
  unsigned short* WeT    = (unsigned short*)ws;                         // 16 MiB
  unsigned short* fusedP = (unsigned short*)(ws + ((size_t)16 << 20));  // 32 MiB
  float*  gw      = (float*)(ws + ((size_t)48 << 20));                  // 128 KiB
  char*   misc    = ws + ((size_t)49 << 20);
  double* lossAcc = (double*)(misc + 0);
  int*    ntiles  = (int*)(misc + 64);
  int4*   tiletab = (int4*)(misc + 256);          // 57 * 16 B
  int*    pair    = (int*)(misc + 4096);          // 32 KiB
  int*    ridx    = (int*)(misc + 4096 + 32768);  // 32 KiB

  gate_kernel<<<dim3(Bsz), 256, 0, stream>>>(x0, x1, x2, x3, Wg, gw, pair);
  bucket_scan<<<dim3(1), 256, 0, stream>>>(pair, ridx, tiletab, ntiles, lossAcc);
  permute_cvt<<<dim3(Bsz), 256, 0, stream>>>(x0, x1, x2, x3, ridx, fusedP);
  we_transpose<<<dim3(NF / 64, NP / 64, NE), 256, 0, stream>>>(We, WeT);
  moe_gemm<<<dim3(MAXTILES * 8), 256, 0, stream>>>(
      fusedP, WeT, gw, be, label, ntiles, tiletab, ridx, out, lossAcc);
  finalize_kernel<<<1, 1, 0, stream>>>(lossAcc, out);
}

// Round 8
// 161.225 us; speedup vs baseline: 2.0471x; 1.0604x over previous
//
#include <hip/hip_runtime.h>
#include <stdint.h>

#define Bsz  8192
#define DMOD 512
#define NE   4
#define NP   1024
#define NF   2048
#define BM   160
#define MAXTILES 57   // sum_b ceil(cnt_b/160) <= ceil(8192/160)+5 = 57

typedef float  f32x4  __attribute__((ext_vector_type(4)));
typedef __bf16 bf16x8 __attribute__((ext_vector_type(8)));
typedef unsigned short u16x8 __attribute__((ext_vector_type(8)));

typedef __attribute__((address_space(3))) void       lds_void;
typedef const __attribute__((address_space(1))) void glb_void;
#define GLOAD16(gp, lp) \
  __builtin_amdgcn_global_load_lds((glb_void*)(gp), (lds_void*)(lp), 16, 0, 0)

__device__ __forceinline__ unsigned short f32_bf16(float f) {
  unsigned int u = __float_as_uint(f);
  u += 0x7FFFu + ((u >> 16) & 1u);   // round-to-nearest-even
  return (unsigned short)(u >> 16);
}

// ---------------- kernel 1: fused gate (blocks 0..8191) + We transpose (8192..10239) --------
__global__ __launch_bounds__(256) void gate_tr(
    const float* __restrict__ x0, const float* __restrict__ x1,
    const float* __restrict__ x2, const float* __restrict__ x3,
    const float* __restrict__ Wg, const float* __restrict__ We,
    float* __restrict__ gw, int* __restrict__ pair,
    unsigned short* __restrict__ WeT)
{
  __shared__ float sred[4][4];
  __shared__ float tsh[64][65];
  const int tid = threadIdx.x;

  if ((int)blockIdx.x < Bsz) {
    // ---- gate: logits -> softmax -> top2 -> gw + pair code ----
    const int b = blockIdx.x;
    const int f = tid * 8;
    const float* xm  = (f < 1024) ? (f < 512 ? x0 : x1) : (f < 1536 ? x2 : x3);
    const float* src = xm + (size_t)b * DMOD + (f & 511);
    float4 v0 = *(const float4*)src;
    float4 v1 = *(const float4*)(src + 4);
    float d[4];
    #pragma unroll
    for (int e = 0; e < 4; ++e) {
      const float* w = Wg + e * NF + f;
      d[e] = v0.x * w[0] + v0.y * w[1] + v0.z * w[2] + v0.w * w[3]
           + v1.x * w[4] + v1.y * w[5] + v1.z * w[6] + v1.w * w[7];
    }
    #pragma unroll
    for (int off = 32; off; off >>= 1) {
      #pragma unroll
      for (int e = 0; e < 4; ++e) d[e] += __shfl_xor(d[e], off);
    }
    if ((tid & 63) == 0) {
      #pragma unroll
      for (int e = 0; e < 4; ++e) sred[tid >> 6][e] = d[e];
    }
    __syncthreads();
    if (tid == 0) {
      float a0 = sred[0][0] + sred[1][0] + sred[2][0] + sred[3][0];
      float a1 = sred[0][1] + sred[1][1] + sred[2][1] + sred[3][1];
      float a2 = sred[0][2] + sred[1][2] + sred[2][2] + sred[3][2];
      float a3 = sred[0][3] + sred[1][3] + sred[2][3] + sred[3][3];
      float m  = fmaxf(fmaxf(a0, a1), fmaxf(a2, a3));
      float e0 = expf(a0 - m), e1 = expf(a1 - m), e2 = expf(a2 - m), e3 = expf(a3 - m);
      float inv = 1.f / (e0 + e1 + e2 + e3);
      float p0 = e0 * inv, p1 = e1 * inv, p2 = e2 * inv, p3 = e3 * inv;
      int i1 = 0; float b1 = a0;                 // jax tie-break: strict >
      if (a1 > b1) { b1 = a1; i1 = 1; }
      if (a2 > b1) { b1 = a2; i1 = 2; }
      if (a3 > b1) { b1 = a3; i1 = 3; }
      int i2 = -1; float b2 = -3.4e38f;
      if (i1 != 0 && a0 > b2) { b2 = a0; i2 = 0; }
      if (i1 != 1 && a1 > b2) { b2 = a1; i2 = 1; }
      if (i1 != 2 && a2 > b2) { b2 = a2; i2 = 2; }
      if (i1 != 3 && a3 > b2) { b2 = a3; i2 = 3; }
      gw[(size_t)b * 4 + 0] = (i1 == 0 || i2 == 0) ? p0 : 0.f;
      gw[(size_t)b * 4 + 1] = (i1 == 1 || i2 == 1) ? p1 : 0.f;
      gw[(size_t)b * 4 + 2] = (i1 == 2 || i2 == 2) ? p2 : 0.f;
      gw[(size_t)b * 4 + 3] = (i1 == 3 || i2 == 3) ? p3 : 0.f;
      // pair code (lo,hi): (0,1)->0 (0,2)->1 (0,3)->2 (1,2)->3 (1,3)->4 (2,3)->5
      int lo = min(i1, i2), hi = max(i1, i2);
      pair[b] = (lo == 0) ? (hi - 1) : (lo == 1) ? (hi + 1) : 5;
    }
  } else {
    // ---- We [E][F][P] f32 -> We_T [E][P][F] bf16 ----
    const int tb = (int)blockIdx.x - Bsz;
    const int e  = tb >> 9;
    const int rem = tb & 511;
    const int tf = (rem & 31) * 64;
    const int tp = (rem >> 5) * 64;
    const int t4 = tid * 4;
    const float* src = We + ((size_t)e * NF + tf) * NP + tp;
    #pragma unroll
    for (int i = 0; i < 4; ++i) {
      int li = i * 1024 + t4;
      int r = li >> 6, c = li & 63;
      float4 v = *(const float4*)(src + (size_t)r * NP + c);
      tsh[c][r] = v.x; tsh[c+1][r] = v.y; tsh[c+2][r] = v.z; tsh[c+3][r] = v.w;
    }
    __syncthreads();
    unsigned short* dst = WeT + ((size_t)e * NP + tp) * NF + tf;
    #pragma unroll
    for (int i = 0; i < 4; ++i) {
      int li = i * 1024 + t4;
      int r = li >> 6, c = li & 63;
      ushort4 o;
      o.x = f32_bf16(tsh[r][c]);   o.y = f32_bf16(tsh[r][c+1]);
      o.z = f32_bf16(tsh[r][c+2]); o.w = f32_bf16(tsh[r][c+3]);
      *(ushort4*)(dst + (size_t)r * NF + c) = o;
    }
  }
}

// ---------------- kernel 2: deterministic single-block bucket scan ----------------
__global__ __launch_bounds__(256) void bucket_scan(
    const int* __restrict__ pair, int* __restrict__ ridx,
    int4* __restrict__ tiletab, int4* __restrict__ bucketTab,
    int* __restrict__ ntiles, double* __restrict__ lossAcc)
{
  __shared__ int cntS[256][6];
  __shared__ int baseS[6];
  const int tid = threadIdx.x;
  int c[6] = {0, 0, 0, 0, 0, 0};
  for (int i = 0; i < 32; ++i) {
    const int code = pair[tid * 32 + i];
    #pragma unroll
    for (int b = 0; b < 6; ++b) c[b] += (code == b) ? 1 : 0;   // static idx (rule #20)
  }
  #pragma unroll
  for (int b = 0; b < 6; ++b) cntS[tid][b] = c[b];
  __syncthreads();
  if (tid < 6) {                 // exclusive scan over 256 per-thread counts
    int run = 0;
    for (int i = 0; i < 256; ++i) { const int v = cntS[i][tid]; cntS[i][tid] = run; run += v; }
    baseS[tid] = run;            // bucket total (temporarily)
  }
  __syncthreads();
  if (tid == 0) {
    const int e1t[6] = {0, 0, 0, 1, 1, 2};
    const int e2t[6] = {1, 2, 3, 2, 3, 3};
    int base[6];
    int off = 0, nt = 0;
    for (int b = 0; b < 6; ++b) {
      base[b] = off;
      const int cb = baseS[b];
      bucketTab[b] = make_int4(off, cb, e1t[b], e2t[b]);
      for (int i = 0; i < cb; i += BM)
        tiletab[nt++] = make_int4(off + i, min(BM, cb - i), e1t[b], e2t[b]);
      off += cb;
    }
    *ntiles = nt;
    *lossAcc = 0.0;
    #pragma unroll
    for (int b = 0; b < 6; ++b) baseS[b] = base[b];
  }
  __syncthreads();
  int pos[6];
  #pragma unroll
  for (int b = 0; b < 6; ++b) pos[b] = baseS[b] + cntS[tid][b];
  for (int i = 0; i < 32; ++i) {
    const int r = tid * 32 + i;
    const int code = pair[r];
    #pragma unroll
    for (int b = 0; b < 6; ++b)
      if (code == b) { ridx[pos[b]] = r; ++pos[b]; }
  }
}

// ---------------- kernel 3a (path A): gather + pre-scale both expert copies ----------------
// fusedP[0][pos] = bf16(w1 * x[ridx[pos]]);  fusedP[1][pos] = bf16(w2 * x[ridx[pos]])
__global__ __launch_bounds__(256) void permute_scale(
    const float* __restrict__ x0, const float* __restrict__ x1,
    const float* __restrict__ x2, const float* __restrict__ x3,
    const int* __restrict__ ridx, const float* __restrict__ gw,
    const int4* __restrict__ bucketTab, unsigned short* __restrict__ fusedP)
{
  const int pos = blockIdx.x;
  int e1 = 0, e2 = 1;
  #pragma unroll
  for (int b = 0; b < 6; ++b) {
    const int4 bt = bucketTab[b];
    if (pos >= bt.x && pos < bt.x + bt.y) { e1 = bt.z; e2 = bt.w; }
  }
  const int ri = ridx[pos];
  const float w1 = gw[(size_t)ri * 4 + e1];
  const float w2 = gw[(size_t)ri * 4 + e2];
  const int tid = threadIdx.x;
  const int f   = tid * 8;
  const float* xm  = (f < 1024) ? (f < 512 ? x0 : x1) : (f < 1536 ? x2 : x3);
  const float* src = xm + (size_t)ri * DMOD + (f & 511);
  float4 v0 = *(const float4*)src;
  float4 v1 = *(const float4*)(src + 4);
  float v[8] = {v0.x, v0.y, v0.z, v0.w, v1.x, v1.y, v1.z, v1.w};
  u16x8 o1, o2;
  #pragma unroll
  for (int j = 0; j < 8; ++j) {
    o1[j] = f32_bf16(v[j] * w1);
    o2[j] = f32_bf16(v[j] * w2);
  }
  *(u16x8*)(fusedP + (size_t)pos * NF + f) = o1;
  *(u16x8*)(fusedP + ((size_t)Bsz + pos) * NF + f) = o2;
}

// ---------------- kernel 3b (path B fallback): gather + cvt only (r7) ----------------
__global__ __launch_bounds__(256) void permute_cvt(
    const float* __restrict__ x0, const float* __restrict__ x1,
    const float* __restrict__ x2, const float* __restrict__ x3,
    const int* __restrict__ ridx, unsigned short* __restrict__ fusedP)
{
  const int pos = blockIdx.x;
  const int r   = ridx[pos];
  const int tid = threadIdx.x;
  const int f   = tid * 8;
  const float* xm  = (f < 1024) ? (f < 512 ? x0 : x1) : (f < 1536 ? x2 : x3);
  const float* src = xm + (size_t)r * DMOD + (f & 511);
  float4 v0 = *(const float4*)src;
  float4 v1 = *(const float4*)(src + 4);
  u16x8 o;
  o[0] = f32_bf16(v0.x); o[1] = f32_bf16(v0.y); o[2] = f32_bf16(v0.z); o[3] = f32_bf16(v0.w);
  o[4] = f32_bf16(v1.x); o[5] = f32_bf16(v1.y); o[6] = f32_bf16(v1.z); o[7] = f32_bf16(v1.w);
  *(u16x8*)(fusedP + (size_t)pos * NF + f) = o;
}

// ---------------- kernel 4a (path A): 8-wave single-acc sparse GEMM (4 waves/SIMD) --------
// 512 thr = 8 waves (2M x 4N), per-wave 80x32, single accT (A pre-scaled per expert copy).
// Depth-2 LDS dbuf, per-wave counted vmcnt (5 or 4), raw s_barrier, XOR-swizzled LDS via
// inverse-swizzled global source. 64 K-steps: t<32 reads A'1 vs We[e1], t>=32 A'2 vs We[e2].
__global__ __launch_bounds__(512, 4) void moe_gemm_v8(
    const unsigned short* __restrict__ fusedP,   // [2][B][F] bf16 scaled copies
    const unsigned short* __restrict__ WeT,      // [E][P][F] bf16
    const float* __restrict__ gw,                // [B][4]
    const float* __restrict__ be,                // [E][P]
    const float* __restrict__ label,             // [B][P]
    const int* __restrict__ ntilesP,
    const int4* __restrict__ tiletab,
    const int* __restrict__ ridx,
    float* __restrict__ out,                     // [0]=loss, [1..] preds
    double* __restrict__ lossAcc)
{
  const int bid  = (int)blockIdx.x;
  const int swz  = (bid & 7) * 57 + (bid >> 3);
  const int tile = swz >> 3;
  if (tile >= *ntilesP) return;
  const int pcol = (swz & 7) * 128;

  __shared__ __align__(16) unsigned short As[2][BM * 64];   // 40 KiB
  __shared__ __align__(16) unsigned short Bs[2][128 * 64];  // 32 KiB
  __shared__ int   ridxS[BM];
  __shared__ float gwS[BM][2];
  __shared__ float red[8];

  const int4 te     = tiletab[tile];
  const int rowbase = te.x;
  const int vcount  = te.y;
  const int e1      = te.z;
  const int e2      = te.w;

  const int tid  = threadIdx.x;
  const int l    = tid & 63;
  const int wave = tid >> 6;      // 0..7
  const int wr   = wave >> 2;     // 0..1 : rows [wr*80, +80)
  const int wc   = wave & 3;      // 0..3 : cols [wc*32, +32)
  const int lrow = l & 15;
  const int g4   = l >> 4;
  const int lr8  = l >> 3;
  const int lc8  = l & 7;
  const int schA = lc8 ^ lr8;     // inverse-swizzled source chunk (stripe base 8-aligned)

  if (tid < BM) {
    const int ri = ridx[rowbase + min(tid, vcount - 1)];
    ridxS[tid]  = ri;
    gwS[tid][0] = gw[(size_t)ri * 4 + e1];
    gwS[tid][1] = gw[(size_t)ri * 4 + e2];
  }
  __syncthreads();

  f32x4 accT[5][2];
  #pragma unroll
  for (int m = 0; m < 5; ++m)
    #pragma unroll
    for (int n = 0; n < 2; ++n) accT[m][n] = f32x4{0.f, 0.f, 0.f, 0.f};

  // stage flat step t: 36 issues (20 A + 16 B) interleaved over 8 waves:
  // wave w takes logical issues {w, w+8, w+16, w+24, w+32(<36)} -> waves 0-3: 5, waves 4-7: 4
  auto STAGE = [&](int t, int buf) {
    const int h  = t >> 5;
    const int k0 = (t & 31) << 6;
    const unsigned short* Ag = fusedP + (size_t)h * ((size_t)Bsz * NF) + k0;
    const unsigned short* Bg = WeT + ((size_t)(h ? e2 : e1) * NP + pcol) * NF + k0;
    #pragma unroll
    for (int s = 0; s < 5; ++s) {
      if (s == 4 && wave >= 4) continue;          // idx >= 36
      const int idx = wave + s * 8;
      if (idx < 20) {
        const int r0  = idx * 8;
        const int row = rowbase + min(r0 + lr8, vcount - 1);
        GLOAD16(Ag + (size_t)row * NF + schA * 8, (char*)(&As[buf][r0 * 64]));
      } else {
        const int r0 = (idx - 20) * 8;
        GLOAD16(Bg + (size_t)(r0 + lr8) * NF + schA * 8, (char*)(&Bs[buf][r0 * 64]));
      }
    }
  };

  auto COMPUTE = [&](int buf) {
    #pragma unroll
    for (int ks = 0; ks < 2; ++ks) {
      bf16x8 af[5], bfr[2];
      #pragma unroll
      for (int m = 0; m < 5; ++m) {
        const int fr = wr * 80 + m * 16 + lrow;
        const int ch = ((g4 + ks * 4) ^ (fr & 7)) * 8;
        af[m] = __builtin_bit_cast(bf16x8, *(const u16x8*)(&As[buf][fr * 64 + ch]));
      }
      #pragma unroll
      for (int n = 0; n < 2; ++n) {
        const int fr = wc * 32 + n * 16 + lrow;
        const int ch = ((g4 + ks * 4) ^ (fr & 7)) * 8;
        bfr[n] = __builtin_bit_cast(bf16x8, *(const u16x8*)(&Bs[buf][fr * 64 + ch]));
      }
      #pragma unroll
      for (int m = 0; m < 5; ++m)
        #pragma unroll
        for (int n = 0; n < 2; ++n)
          accT[m][n] = __builtin_amdgcn_mfma_f32_16x16x32_bf16(af[m], bfr[n], accT[m][n], 0, 0, 0);
    }
  };

  STAGE(0, 0);
  STAGE(1, 1);

  #pragma unroll 1
  for (int t = 0; t < 64; ++t) {
    const int buf = t & 1;
    // per-wave ledger: outstanding newer-than-t = own issues of batch t+1 (5 or 4); 0 at t=63
    if (t == 63)          { asm volatile("s_waitcnt vmcnt(0)" ::: "memory"); }
    else if (wave < 4)    { asm volatile("s_waitcnt vmcnt(5)" ::: "memory"); }
    else                  { asm volatile("s_waitcnt vmcnt(4)" ::: "memory"); }
    __builtin_amdgcn_s_barrier();          // batch-t loads landed for all waves
    COMPUTE(buf);
    __builtin_amdgcn_sched_barrier(0);     // pin ds_reads+MFMAs before the barrier
    __builtin_amdgcn_s_barrier();          // every wave done reading buf
    if (t < 62) STAGE(t + 2, buf);         // overwrite freed buffer
  }

  // epilogue: bias, masked scatter-store of preds, fused MSE partial
  float lsum = 0.f;
  #pragma unroll
  for (int m = 0; m < 5; ++m) {
    #pragma unroll
    for (int r = 0; r < 4; ++r) {
      const int lrowi = wr * 80 + m * 16 + g4 * 4 + r;
      const bool valid = lrowi < vcount;
      const int grow = ridxS[lrowi];
      const float w1 = gwS[lrowi][0];
      const float w2 = gwS[lrowi][1];
      #pragma unroll
      for (int n = 0; n < 2; ++n) {
        const int gcol = pcol + wc * 32 + n * 16 + lrow;
        float bias = w1 * be[e1 * NP + gcol] + w2 * be[e2 * NP + gcol];
        float pred = accT[m][n][r] + bias;
        if (valid) {
          out[1 + (size_t)grow * NP + gcol] = pred;
          float d = pred - label[(size_t)grow * NP + gcol];
          lsum += d * d;
        }
      }
    }
  }
  #pragma unroll
  for (int off = 32; off; off >>= 1) lsum += __shfl_xor(lsum, off);
  if (l == 0) red[wave] = lsum;
  __syncthreads();
  if (tid == 0) {
    double s = 0.0;
    #pragma unroll
    for (int w = 0; w < 8; ++w) s += (double)red[w];
    atomicAdd(lossAcc, s);
  }
}

// ---------------- kernel 4b (path B fallback): r7 4-wave dual-acc GEMM ----------------
__global__ __launch_bounds__(256, 2) void moe_gemm_r7(
    const unsigned short* __restrict__ fusedP,   // [B][F] bf16, bucket order
    const unsigned short* __restrict__ WeT,
    const float* __restrict__ gw,
    const float* __restrict__ be,
    const float* __restrict__ label,
    const int* __restrict__ ntilesP,
    const int4* __restrict__ tiletab,
    const int* __restrict__ ridx,
    float* __restrict__ out,
    double* __restrict__ lossAcc)
{
  const int bid  = (int)blockIdx.x;
  const int swz  = (bid & 7) * 57 + (bid >> 3);
  const int tile = swz >> 3;
  if (tile >= *ntilesP) return;
  const int pcol = (swz & 7) * 128;

  __shared__ __align__(16) unsigned short As[2][BM * 64];
  __shared__ __align__(16) unsigned short Bs[2][128 * 64];
  __shared__ int   ridxS[BM];
  __shared__ float gwS[BM][2];
  __shared__ float red[4];

  const int4 te     = tiletab[tile];
  const int rowbase = te.x;
  const int vcount  = te.y;
  const int e1      = te.z;
  const int e2      = te.w;

  const int tid  = threadIdx.x;
  const int l    = tid & 63;
  const int wave = tid >> 6;
  const int wr   = wave >> 1;
  const int wc   = wave & 1;
  const int lrow = l & 15;
  const int g4   = l >> 4;
  const int lr8  = l >> 3;
  const int lc8  = l & 7;
  const int schA = lc8 ^ lr8;

  if (tid < BM) {
    const int ri = ridx[rowbase + min(tid, vcount - 1)];
    ridxS[tid]  = ri;
    gwS[tid][0] = gw[(size_t)ri * 4 + e1];
    gwS[tid][1] = gw[(size_t)ri * 4 + e2];
  }
  __syncthreads();

  int rowA[5];
  #pragma unroll
  for (int i = 0; i < 5; ++i)
    rowA[i] = rowbase + min(wave * 40 + i * 8 + lr8, vcount - 1);

  f32x4 accT[5][4], accE[5][4];
  #pragma unroll
  for (int m = 0; m < 5; ++m)
    #pragma unroll
    for (int n = 0; n < 4; ++n) {
      accT[m][n] = f32x4{0.f, 0.f, 0.f, 0.f};
      accE[m][n] = f32x4{0.f, 0.f, 0.f, 0.f};
    }

  auto STAGE = [&](int t, int buf) {
    const int e  = (t >> 5) ? e2 : e1;
    const int k0 = (t & 31) << 6;
    const unsigned short* Bg = WeT + ((size_t)e * NP + pcol) * NF + k0;
    #pragma unroll
    for (int i = 0; i < 5; ++i) {
      const int r0 = wave * 40 + i * 8;
      GLOAD16(fusedP + (size_t)rowA[i] * NF + k0 + schA * 8, (char*)(&As[buf][r0 * 64]));
    }
    #pragma unroll
    for (int i = 0; i < 4; ++i) {
      const int r0 = wave * 32 + i * 8;
      GLOAD16(Bg + (size_t)(r0 + lr8) * NF + schA * 8, (char*)(&Bs[buf][r0 * 64]));
    }
  };

  auto COMPUTE = [&](int buf) {
    #pragma unroll
    for (int ks = 0; ks < 2; ++ks) {
      bf16x8 af[5], bfr[4];
      #pragma unroll
      for (int m = 0; m < 5; ++m) {
        const int fr = wr * 80 + m * 16 + lrow;
        const int ch = ((g4 + ks * 4) ^ (fr & 7)) * 8;
        af[m] = __builtin_bit_cast(bf16x8, *(const u16x8*)(&As[buf][fr * 64 + ch]));
      }
      #pragma unroll
      for (int n = 0; n < 4; ++n) {
        const int fr = wc * 64 + n * 16 + lrow;
        const int ch = ((g4 + ks * 4) ^ (fr & 7)) * 8;
        bfr[n] = __builtin_bit_cast(bf16x8, *(const u16x8*)(&Bs[buf][fr * 64 + ch]));
      }
      #pragma unroll
      for (int m = 0; m < 5; ++m)
        #pragma unroll
        for (int n = 0; n < 4; ++n)
          accE[m][n] = __builtin_amdgcn_mfma_f32_16x16x32_bf16(af[m], bfr[n], accE[m][n], 0, 0, 0);
    }
  };

  auto FOLD = [&](int ei) {
    #pragma unroll
    for (int m = 0; m < 5; ++m)
      #pragma unroll
      for (int r = 0; r < 4; ++r) {
        const float wv = gwS[wr * 80 + m * 16 + g4 * 4 + r][ei];
        #pragma unroll
        for (int n = 0; n < 4; ++n) {
          accT[m][n][r] += wv * accE[m][n][r];
          accE[m][n][r] = 0.f;
        }
      }
  };

  STAGE(0, 0);
  STAGE(1, 1);

  #pragma unroll 1
  for (int t = 0; t < 64; ++t) {
    const int buf = t & 1;
    if (t == 63) asm volatile("s_waitcnt vmcnt(0)" ::: "memory");
    else         asm volatile("s_waitcnt vmcnt(9)" ::: "memory");
    __builtin_amdgcn_s_barrier();
    COMPUTE(buf);
    if ((t & 31) == 31) FOLD(t >> 5);
    __builtin_amdgcn_sched_barrier(0);
    __builtin_amdgcn_s_barrier();
    if (t < 62) STAGE(t + 2, buf);
  }

  float lsum = 0.f;
  #pragma unroll
  for (int m = 0; m < 5; ++m) {
    #pragma unroll
    for (int r = 0; r < 4; ++r) {
      const int lrowi = wr * 80 + m * 16 + g4 * 4 + r;
      const bool valid = lrowi < vcount;
      const int grow = ridxS[lrowi];
      const float w1 = gwS[lrowi][0];
      const float w2 = gwS[lrowi][1];
      #pragma unroll
      for (int n = 0; n < 4; ++n) {
        const int gcol = pcol + wc * 64 + n * 16 + lrow;
        float bias = w1 * be[e1 * NP + gcol] + w2 * be[e2 * NP + gcol];
        float pred = accT[m][n][r] + bias;
        if (valid) {
          out[1 + (size_t)grow * NP + gcol] = pred;
          float d = pred - label[(size_t)grow * NP + gcol];
          lsum += d * d;
        }
      }
    }
  }
  #pragma unroll
  for (int off = 32; off; off >>= 1) lsum += __shfl_xor(lsum, off);
  if (l == 0) red[wave] = lsum;
  __syncthreads();
  if (tid == 0) {
    double s = (double)red[0] + (double)red[1] + (double)red[2] + (double)red[3];
    atomicAdd(lossAcc, s);
  }
}

// ---------------- kernel 5: finalize loss ----------------
__global__ void finalize_kernel(const double* __restrict__ lossAcc, float* __restrict__ out) {
  out[0] = (float)(*lossAcc * (1.0 / ((double)Bsz * (double)NP)));
}

extern "C" void kernel_launch(void* const* d_in, const int* in_sizes, int n_in,
                              void* d_out, int out_size, void* d_ws, size_t ws_size,
                              hipStream_t stream) {
  const float* x0    = (const float*)d_in[0];
  const float* x1    = (const float*)d_in[1];
  const float* x2    = (const float*)d_in[2];
  const float* x3    = (const float*)d_in[3];
  const float* label = (const float*)d_in[4];
  const float* Wg    = (const float*)d_in[5];
  const float* We    = (const float*)d_in[6];
  const float* be    = (const float*)d_in[7];
  float* out = (float*)d_out;
  char* ws = (char*)d_ws;

  const bool bigWs = ws_size >= ((size_t)82 << 20);

  if (bigWs) {
    // Path A layout: WeT @0 (16M) | fusedP [2][B][F] @16M (64M) | misc @80M
    unsigned short* WeT    = (unsigned short*)ws;
    unsigned short* fusedP = (unsigned short*)(ws + ((size_t)16 << 20));
    char*   misc    = ws + ((size_t)80 << 20);
    double* lossAcc = (double*)(misc + 0);
    int*    ntiles  = (int*)(misc + 64);
    int4*   tiletab = (int4*)(misc + 256);           // 57 * 16 B
    int4*   bucketTab = (int4*)(misc + 2048);        // 6 * 16 B
    int*    pair    = (int*)(misc + 4096);           // 32 KiB
    int*    ridx    = (int*)(misc + 4096 + 32768);   // 32 KiB
    float*  gw      = (float*)(misc + 4096 + 65536); // 128 KiB

    gate_tr<<<dim3(Bsz + 2048), 256, 0, stream>>>(x0, x1, x2, x3, Wg, We, gw, pair, WeT);
    bucket_scan<<<dim3(1), 256, 0, stream>>>(pair, ridx, tiletab, bucketTab, ntiles, lossAcc);
    permute_scale<<<dim3(Bsz), 256, 0, stream>>>(x0, x1, x2, x3, ridx, gw, bucketTab, fusedP);
    moe_gemm_v8<<<dim3(MAXTILES * 8), 512, 0, stream>>>(
        fusedP, WeT, gw, be, label, ntiles, tiletab, ridx, out, lossAcc);
    finalize_kernel<<<1, 1, 0, stream>>>(lossAcc, out);
  } else {
    // Path B (r7 fallback) layout: WeT @0 | fusedP @16M (32M) | gw @48M | misc @49M
    unsigned short* WeT    = (unsigned short*)ws;
    unsigned short* fusedP = (unsigned short*)(ws + ((size_t)16 << 20));
    float*  gw      = (float*)(ws + ((size_t)48 << 20));
    char*   misc    = ws + ((size_t)49 << 20);
    double* lossAcc = (double*)(misc + 0);
    int*    ntiles  = (int*)(misc + 64);
    int4*   tiletab = (int4*)(misc + 256);
    int4*   bucketTab = (int4*)(misc + 2048);
    int*    pair    = (int*)(misc + 4096);
    int*    ridx    = (int*)(misc + 4096 + 32768);

    gate_tr<<<dim3(Bsz + 2048), 256, 0, stream>>>(x0, x1, x2, x3, Wg, We, gw, pair, WeT);
    bucket_scan<<<dim3(1), 256, 0, stream>>>(pair, ridx, tiletab, bucketTab, ntiles, lossAcc);
    permute_cvt<<<dim3(Bsz), 256, 0, stream>>>(x0, x1, x2, x3, ridx, fusedP);
    moe_gemm_r7<<<dim3(MAXTILES * 8), 256, 0, stream>>>(
        fusedP, WeT, gw, be, label, ntiles, tiletab, ridx, out, lossAcc);
    finalize_kernel<<<1, 1, 0, stream>>>(lossAcc, out);
  }
}

// Round 9
// 141.743 us; speedup vs baseline: 2.3285x; 1.1374x over previous
//
#include <hip/hip_runtime.h>
#include <stdint.h>

#define Bsz  8192
#define DMOD 512
#define NE   4
#define NP   1024
#define NF   2048
#define BM   160
#define MAXTILES 57   // sum_b ceil(cnt_b/160) <= ceil(8192/160)+5 = 57

typedef float  f32x4  __attribute__((ext_vector_type(4)));
typedef __bf16 bf16x8 __attribute__((ext_vector_type(8)));
typedef unsigned short u16x8 __attribute__((ext_vector_type(8)));

typedef __attribute__((address_space(3))) void       lds_void;
typedef const __attribute__((address_space(1))) void glb_void;
#define GLOAD16(gp, lp) \
  __builtin_amdgcn_global_load_lds((glb_void*)(gp), (lds_void*)(lp), 16, 0, 0)

__device__ __forceinline__ unsigned short f32_bf16(float f) {
  unsigned int u = __float_as_uint(f);
  u += 0x7FFFu + ((u >> 16) & 1u);   // round-to-nearest-even
  return (unsigned short)(u >> 16);
}

// ---------------- kernel 1: gate + fusedB write (blocks 0..8191) | We transpose (rest) ------
__global__ __launch_bounds__(256) void gate_fuse(
    const float* __restrict__ x0, const float* __restrict__ x1,
    const float* __restrict__ x2, const float* __restrict__ x3,
    const float* __restrict__ Wg, const float* __restrict__ We,
    float* __restrict__ gw, int* __restrict__ pair,
    unsigned short* __restrict__ fusedB, unsigned short* __restrict__ WeT)
{
  __shared__ float sred[4][4];
  __shared__ float tsh[64][65];
  const int tid = threadIdx.x;

  if ((int)blockIdx.x < Bsz) {
    // ---- gate: logits -> softmax -> top2 -> gw + pair code; also emit bf16 row ----
    const int b = blockIdx.x;
    const int f = tid * 8;
    const float* xm  = (f < 1024) ? (f < 512 ? x0 : x1) : (f < 1536 ? x2 : x3);
    const float* src = xm + (size_t)b * DMOD + (f & 511);
    float4 v0 = *(const float4*)src;
    float4 v1 = *(const float4*)(src + 4);
    u16x8 o;
    o[0] = f32_bf16(v0.x); o[1] = f32_bf16(v0.y); o[2] = f32_bf16(v0.z); o[3] = f32_bf16(v0.w);
    o[4] = f32_bf16(v1.x); o[5] = f32_bf16(v1.y); o[6] = f32_bf16(v1.z); o[7] = f32_bf16(v1.w);
    *(u16x8*)(fusedB + (size_t)b * NF + f) = o;

    float d[4];
    #pragma unroll
    for (int e = 0; e < 4; ++e) {
      const float* w = Wg + e * NF + f;
      d[e] = v0.x * w[0] + v0.y * w[1] + v0.z * w[2] + v0.w * w[3]
           + v1.x * w[4] + v1.y * w[5] + v1.z * w[6] + v1.w * w[7];
    }
    #pragma unroll
    for (int off = 32; off; off >>= 1) {
      #pragma unroll
      for (int e = 0; e < 4; ++e) d[e] += __shfl_xor(d[e], off);
    }
    if ((tid & 63) == 0) {
      #pragma unroll
      for (int e = 0; e < 4; ++e) sred[tid >> 6][e] = d[e];
    }
    __syncthreads();
    if (tid == 0) {
      float a0 = sred[0][0] + sred[1][0] + sred[2][0] + sred[3][0];
      float a1 = sred[0][1] + sred[1][1] + sred[2][1] + sred[3][1];
      float a2 = sred[0][2] + sred[1][2] + sred[2][2] + sred[3][2];
      float a3 = sred[0][3] + sred[1][3] + sred[2][3] + sred[3][3];
      float m  = fmaxf(fmaxf(a0, a1), fmaxf(a2, a3));
      float e0 = expf(a0 - m), e1 = expf(a1 - m), e2 = expf(a2 - m), e3 = expf(a3 - m);
      float inv = 1.f / (e0 + e1 + e2 + e3);
      float p0 = e0 * inv, p1 = e1 * inv, p2 = e2 * inv, p3 = e3 * inv;
      int i1 = 0; float b1 = a0;                 // jax tie-break: strict >
      if (a1 > b1) { b1 = a1; i1 = 1; }
      if (a2 > b1) { b1 = a2; i1 = 2; }
      if (a3 > b1) { b1 = a3; i1 = 3; }
      int i2 = -1; float b2 = -3.4e38f;
      if (i1 != 0 && a0 > b2) { b2 = a0; i2 = 0; }
      if (i1 != 1 && a1 > b2) { b2 = a1; i2 = 1; }
      if (i1 != 2 && a2 > b2) { b2 = a2; i2 = 2; }
      if (i1 != 3 && a3 > b2) { b2 = a3; i2 = 3; }
      gw[(size_t)b * 4 + 0] = (i1 == 0 || i2 == 0) ? p0 : 0.f;
      gw[(size_t)b * 4 + 1] = (i1 == 1 || i2 == 1) ? p1 : 0.f;
      gw[(size_t)b * 4 + 2] = (i1 == 2 || i2 == 2) ? p2 : 0.f;
      gw[(size_t)b * 4 + 3] = (i1 == 3 || i2 == 3) ? p3 : 0.f;
      // pair code (lo,hi): (0,1)->0 (0,2)->1 (0,3)->2 (1,2)->3 (1,3)->4 (2,3)->5
      int lo = min(i1, i2), hi = max(i1, i2);
      pair[b] = (lo == 0) ? (hi - 1) : (lo == 1) ? (hi + 1) : 5;
    }
  } else {
    // ---- We [E][F][P] f32 -> We_T [E][P][F] bf16 ----
    const int tb = (int)blockIdx.x - Bsz;
    const int e  = tb >> 9;
    const int rem = tb & 511;
    const int tf = (rem & 31) * 64;
    const int tp = (rem >> 5) * 64;
    const int t4 = tid * 4;
    const float* src = We + ((size_t)e * NF + tf) * NP + tp;
    #pragma unroll
    for (int i = 0; i < 4; ++i) {
      int li = i * 1024 + t4;
      int r = li >> 6, c = li & 63;
      float4 v = *(const float4*)(src + (size_t)r * NP + c);
      tsh[c][r] = v.x; tsh[c+1][r] = v.y; tsh[c+2][r] = v.z; tsh[c+3][r] = v.w;
    }
    __syncthreads();
    unsigned short* dst = WeT + ((size_t)e * NP + tp) * NF + tf;
    #pragma unroll
    for (int i = 0; i < 4; ++i) {
      int li = i * 1024 + t4;
      int r = li >> 6, c = li & 63;
      ushort4 o;
      o.x = f32_bf16(tsh[r][c]);   o.y = f32_bf16(tsh[r][c+1]);
      o.z = f32_bf16(tsh[r][c+2]); o.w = f32_bf16(tsh[r][c+3]);
      *(ushort4*)(dst + (size_t)r * NF + c) = o;
    }
  }
}

// ---------------- kernel 2: deterministic single-block bucket scan ----------------
__global__ __launch_bounds__(256) void bucket_scan(
    const int* __restrict__ pair, int* __restrict__ ridx,
    int4* __restrict__ tiletab, int* __restrict__ ntiles,
    double* __restrict__ lossAcc)
{
  __shared__ int cntS[256][6];
  __shared__ int baseS[6];
  const int tid = threadIdx.x;
  int c[6] = {0, 0, 0, 0, 0, 0};
  for (int i = 0; i < 32; ++i) {
    const int code = pair[tid * 32 + i];
    #pragma unroll
    for (int b = 0; b < 6; ++b) c[b] += (code == b) ? 1 : 0;   // static idx (rule #20)
  }
  #pragma unroll
  for (int b = 0; b < 6; ++b) cntS[tid][b] = c[b];
  __syncthreads();
  if (tid < 6) {                 // exclusive scan over 256 per-thread counts
    int run = 0;
    for (int i = 0; i < 256; ++i) { const int v = cntS[i][tid]; cntS[i][tid] = run; run += v; }
    baseS[tid] = run;            // bucket total (temporarily)
  }
  __syncthreads();
  if (tid == 0) {
    const int e1t[6] = {0, 0, 0, 1, 1, 2};
    const int e2t[6] = {1, 2, 3, 2, 3, 3};
    int base[6];
    int off = 0, nt = 0;
    for (int b = 0; b < 6; ++b) {
      base[b] = off;
      const int cb = baseS[b];
      for (int i = 0; i < cb; i += BM)
        tiletab[nt++] = make_int4(off + i, min(BM, cb - i), e1t[b], e2t[b]);
      off += cb;
    }
    *ntiles = nt;
    *lossAcc = 0.0;
    #pragma unroll
    for (int b = 0; b < 6; ++b) baseS[b] = base[b];
  }
  __syncthreads();
  int pos[6];
  #pragma unroll
  for (int b = 0; b < 6; ++b) pos[b] = baseS[b] + cntS[tid][b];
  for (int i = 0; i < 32; ++i) {
    const int r = tid * 32 + i;
    const int code = pair[r];
    #pragma unroll
    for (int b = 0; b < 6; ++b)
      if (code == b) { ridx[pos[b]] = r; ++pos[b]; }
  }
}

// ---------------- kernel 3: dual-expert-B sparse GEMM (BK=32, 8 waves, 4/SIMD) ----------
// Per iter: ONE gathered A-tile (160x32) + TWO B-panels (128x32 per expert); 20 MFMA into
// acc1/acc2; gate weights applied only in the epilogue. A staged/read once per K-position
// (vs twice in r8). Depth-2 LDS dbuf, counted vmcnt, raw s_barrier, XOR swizzle
// (BK=32 key = (row>>1)&3; source chunk (l&3)^((l>>3)&3), read chunk g4^((fr>>1)&3)).
__global__ __launch_bounds__(512, 4) void moe_gemm_db(
    const unsigned short* __restrict__ fusedB,   // [B][F] bf16, ORIGINAL row order
    const unsigned short* __restrict__ WeT,      // [E][P][F] bf16
    const float* __restrict__ gw,                // [B][4]
    const float* __restrict__ be,                // [E][P]
    const float* __restrict__ label,             // [B][P]
    const int* __restrict__ ntilesP,
    const int4* __restrict__ tiletab,
    const int* __restrict__ ridx,
    float* __restrict__ out,                     // [0]=loss, [1..] preds
    double* __restrict__ lossAcc)
{
  const int bid  = (int)blockIdx.x;
  const int swz  = (bid & 7) * 57 + (bid >> 3);
  const int tile = swz >> 3;
  if (tile >= *ntilesP) return;
  const int pcol = (swz & 7) * 128;

  __shared__ __align__(16) unsigned short As[2][BM * 32];    // 20 KiB
  __shared__ __align__(16) unsigned short B1s[2][128 * 32];  // 16 KiB
  __shared__ __align__(16) unsigned short B2s[2][128 * 32];  // 16 KiB
  __shared__ int   ridxS[BM];
  __shared__ float gwS[BM][2];
  __shared__ float red[8];

  const int4 te     = tiletab[tile];
  const int rowbase = te.x;
  const int vcount  = te.y;
  const int e1      = te.z;
  const int e2      = te.w;

  const int tid  = threadIdx.x;
  const int l    = tid & 63;
  const int wave = tid >> 6;      // 0..7
  const int wr   = wave >> 2;     // 0..1 : rows [wr*80, +80)
  const int wc   = wave & 3;      // 0..3 : cols [wc*32, +32)
  const int lrow = l & 15;
  const int g4   = l >> 4;
  const int schA = (l & 3) ^ ((l >> 3) & 3);   // inverse-swizzled source chunk (lane-const)

  if (tid < BM) {
    const int ri = ridx[rowbase + min(tid, vcount - 1)];
    ridxS[tid]  = ri;
    gwS[tid][0] = gw[(size_t)ri * 4 + e1];
    gwS[tid][1] = gw[(size_t)ri * 4 + e2];
  }
  __syncthreads();

  // gathered global rows for this lane's A staging stripes (16 rows per issue):
  // wave w stages A stripe w; waves 0,1 also stripe 8+w.
  const int rowA0 = ridxS[wave * 16 + (l >> 2)];
  const int rowA1 = (wave < 2) ? ridxS[(8 + wave) * 16 + (l >> 2)] : 0;

  f32x4 acc1[5][2], acc2[5][2];
  #pragma unroll
  for (int m = 0; m < 5; ++m)
    #pragma unroll
    for (int n = 0; n < 2; ++n) {
      acc1[m][n] = f32x4{0.f, 0.f, 0.f, 0.f};
      acc2[m][n] = f32x4{0.f, 0.f, 0.f, 0.f};
    }

  // stage K-step t: 26 issues (10 A + 8 B1 + 8 B2); wave w -> idx {w, w+8, w+16, w+24<26}
  auto STAGE = [&](int t, int buf) {
    const int k0 = t << 5;
    const unsigned short* B1g = WeT + ((size_t)e1 * NP + pcol) * NF + k0;
    const unsigned short* B2g = WeT + ((size_t)e2 * NP + pcol) * NF + k0;
    #pragma unroll
    for (int s = 0; s < 4; ++s) {
      const int idx = wave + s * 8;
      if (idx >= 26) continue;
      if (idx < 10) {
        const int r0  = idx * 16;
        const int row = (s == 0) ? rowA0 : rowA1;
        GLOAD16(fusedB + (size_t)row * NF + k0 + schA * 8, (char*)(&As[buf][r0 * 32]));
      } else if (idx < 18) {
        const int r0 = (idx - 10) * 16;
        GLOAD16(B1g + (size_t)(r0 + (l >> 2)) * NF + schA * 8, (char*)(&B1s[buf][r0 * 32]));
      } else {
        const int r0 = (idx - 18) * 16;
        GLOAD16(B2g + (size_t)(r0 + (l >> 2)) * NF + schA * 8, (char*)(&B2s[buf][r0 * 32]));
      }
    }
  };

  auto COMPUTE = [&](int buf) {
    bf16x8 af[5], b1f[2], b2f[2];
    #pragma unroll
    for (int m = 0; m < 5; ++m) {
      const int fr = wr * 80 + m * 16 + lrow;
      const int ch = (g4 ^ ((fr >> 1) & 3)) * 8;
      af[m] = __builtin_bit_cast(bf16x8, *(const u16x8*)(&As[buf][fr * 32 + ch]));
    }
    #pragma unroll
    for (int n = 0; n < 2; ++n) {
      const int fr = wc * 32 + n * 16 + lrow;
      const int ch = (g4 ^ ((fr >> 1) & 3)) * 8;
      b1f[n] = __builtin_bit_cast(bf16x8, *(const u16x8*)(&B1s[buf][fr * 32 + ch]));
      b2f[n] = __builtin_bit_cast(bf16x8, *(const u16x8*)(&B2s[buf][fr * 32 + ch]));
    }
    #pragma unroll
    for (int m = 0; m < 5; ++m)
      #pragma unroll
      for (int n = 0; n < 2; ++n) {
        acc1[m][n] = __builtin_amdgcn_mfma_f32_16x16x32_bf16(af[m], b1f[n], acc1[m][n], 0, 0, 0);
        acc2[m][n] = __builtin_amdgcn_mfma_f32_16x16x32_bf16(af[m], b2f[n], acc2[m][n], 0, 0, 0);
      }
  };

  STAGE(0, 0);
  STAGE(1, 1);

  #pragma unroll 1
  for (int t = 0; t < 64; ++t) {
    const int buf = t & 1;
    // per-wave ledger: outstanding newer than batch t = own issues of t+1 (4 or 3); 0 at 63
    if (t == 63)       { asm volatile("s_waitcnt vmcnt(0)" ::: "memory"); }
    else if (wave < 2) { asm volatile("s_waitcnt vmcnt(4)" ::: "memory"); }
    else               { asm volatile("s_waitcnt vmcnt(3)" ::: "memory"); }
    __builtin_amdgcn_s_barrier();          // batch-t loads landed for all waves
    COMPUTE(buf);
    __builtin_amdgcn_sched_barrier(0);     // pin ds_reads+MFMAs before the barrier
    __builtin_amdgcn_s_barrier();          // every wave done reading buf
    if (t < 62) STAGE(t + 2, buf);         // overwrite freed buffer
  }

  // epilogue: pred = w1*acc1 + w2*acc2 + w1*be1 + w2*be2; masked scatter; fused MSE
  float lsum = 0.f;
  #pragma unroll
  for (int m = 0; m < 5; ++m) {
    #pragma unroll
    for (int r = 0; r < 4; ++r) {
      const int lrowi = wr * 80 + m * 16 + g4 * 4 + r;
      const bool valid = lrowi < vcount;
      const int grow = ridxS[lrowi];
      const float w1 = gwS[lrowi][0];
      const float w2 = gwS[lrowi][1];
      #pragma unroll
      for (int n = 0; n < 2; ++n) {
        const int gcol = pcol + wc * 32 + n * 16 + lrow;
        float pred = w1 * (acc1[m][n][r] + be[e1 * NP + gcol])
                   + w2 * (acc2[m][n][r] + be[e2 * NP + gcol]);
        if (valid) {
          out[1 + (size_t)grow * NP + gcol] = pred;
          float d = pred - label[(size_t)grow * NP + gcol];
          lsum += d * d;
        }
      }
    }
  }
  #pragma unroll
  for (int off = 32; off; off >>= 1) lsum += __shfl_xor(lsum, off);
  if (l == 0) red[wave] = lsum;
  __syncthreads();
  if (tid == 0) {
    double s = 0.0;
    #pragma unroll
    for (int w = 0; w < 8; ++w) s += (double)red[w];
    atomicAdd(lossAcc, s);
  }
}

// ---------------- kernel 4: finalize loss ----------------
__global__ void finalize_kernel(const double* __restrict__ lossAcc, float* __restrict__ out) {
  out[0] = (float)(*lossAcc * (1.0 / ((double)Bsz * (double)NP)));
}

extern "C" void kernel_launch(void* const* d_in, const int* in_sizes, int n_in,
                              void* d_out, int out_size, void* d_ws, size_t ws_size,
                              hipStream_t stream) {
  const float* x0    = (const float*)d_in[0];
  const float* x1    = (const float*)d_in[1];
  const float* x2    = (const float*)d_in[2];
  const float* x3    = (const float*)d_in[3];
  const float* label = (const float*)d_in[4];
  const float* Wg    = (const float*)d_in[5];
  const float* We    = (const float*)d_in[6];
  const float* be    = (const float*)d_in[7];
  float* out = (float*)d_out;

  char* ws = (char*)d_ws;
  unsigned short* WeT    = (unsigned short*)ws;                         // 16 MiB
  unsigned short* fusedB = (unsigned short*)(ws + ((size_t)16 << 20));  // 32 MiB
  float*  gw      = (float*)(ws + ((size_t)48 << 20));                  // 128 KiB
  char*   misc    = ws + ((size_t)49 << 20);
  double* lossAcc = (double*)(misc + 0);
  int*    ntiles  = (int*)(misc + 64);
  int4*   tiletab = (int4*)(misc + 256);          // 57 * 16 B
  int*    pair    = (int*)(misc + 4096);          // 32 KiB
  int*    ridx    = (int*)(misc + 4096 + 32768);  // 32 KiB

  gate_fuse<<<dim3(Bsz + 2048), 256, 0, stream>>>(x0, x1, x2, x3, Wg, We, gw, pair, fusedB, WeT);
  bucket_scan<<<dim3(1), 256, 0, stream>>>(pair, ridx, tiletab, ntiles, lossAcc);
  moe_gemm_db<<<dim3(MAXTILES * 8), 512, 0, stream>>>(
      fusedB, WeT, gw, be, label, ntiles, tiletab, ridx, out, lossAcc);
  finalize_kernel<<<1, 1, 0, stream>>>(lossAcc, out);
}